// Round 9
// baseline (271.620 us; speedup 1.0000x reference)
//
#include <hip/hip_runtime.h>

#define NNODES 50000
#define NEDGES 1600000
#define IN_CH 256
#define HEADS 4
#define OUT_CH 32
#define HC 128                       // HEADS*OUT_CH
#define NSB ((NNODES + 255) / 256)   // 196 scan blocks
#define NCHUNK 128
#define CE 12500                     // edges per chunk; 128*12500 == NEDGES
#define WORDS 25000                  // u32 words per chunk hist (2 u16 bins/word)

typedef unsigned int u32;
typedef unsigned short u16;
typedef short bf16x8 __attribute__((ext_vector_type(8)));   // 8 bf16 in 4 VGPRs
typedef u16 u16x8 __attribute__((ext_vector_type(8)));
typedef float f32x4 __attribute__((ext_vector_type(4)));

__device__ __forceinline__ float b2f(u16 s) { return __uint_as_float(((u32)s) << 16); }
__device__ __forceinline__ u16 f2b(float f) {
  u32 u = __float_as_uint(f);
  u32 r = (u + 0x7FFFu + ((u >> 16) & 1u)) >> 16;
  return (u16)r;
}
__device__ __forceinline__ float lrelu(float v) { return v >= 0.f ? v : 0.2f * v; }

// node record layout (16 floats = 64B): [0:4)=s_src, [4:8)=s_dst, [8:12)=mx, [12:16)=rden
#define NR 16

// ---- K0: W (256x128 f32) -> bf16, transposed+tiled: wt[((kt*128+n)*32+kk)] ----
__global__ __launch_bounds__(256) void k_wprep(const float* __restrict__ W,
                                               u16* __restrict__ wt) {
  int i = blockIdx.x * 256 + threadIdx.x;   // 0..32767
  if (i >= IN_CH * HC) return;
  int kk = i & 31;
  int n = (i >> 5) & 127;
  int kt = i >> 12;
  wt[i] = f2b(W[(size_t)(kt * 32 + kk) * HC + n]);
}

// ---- K1: h = x @ W via bf16 MFMA (x split hi+lo); hb stored as per-head planes ----
__global__ __launch_bounds__(256) void k_gemm(const float* __restrict__ x,
                                              const u16* __restrict__ wt,
                                              const float* __restrict__ attn,
                                              u16* __restrict__ hb,
                                              float* __restrict__ nrec) {
  __shared__ union {
    struct {
      u16 xh[64 * 32];    // 4 KB, XOR-swizzled
      u16 xl[64 * 32];    // 4 KB
      u16 wh[128 * 32];   // 8 KB
    } st;
    float cbuf[64 * 132]; // 33.8 KB (row stride 132 f32)
  } L;
  __shared__ float sA[256];
  const int tid = threadIdx.x;
  const int wave = tid >> 6;
  const int lane = tid & 63;
  const int row0 = blockIdx.x * 64;
  sA[tid] = attn[tid];

  f32x4 acc[4][2] = {};           // [mi 16-row frag][ni 16-col frag]
  const int frow = lane & 15;
  const int koff = (lane >> 4) << 4;

  const int sr = tid >> 2;
  const int skc = (tid & 3) << 3;
  const int sgrow = row0 + sr;
  const int sxb = (sr << 6) + (skc << 1);
  const int sxs = sxb ^ ((sr & 7) << 4);

  for (int kt = 0; kt < 8; ++kt) {
    {
      float4 v0 = make_float4(0.f, 0.f, 0.f, 0.f), v1 = v0;
      if (sgrow < NNODES) {
        const float* px = &x[(size_t)sgrow * IN_CH + kt * 32 + skc];
        v0 = *(const float4*)px;
        v1 = *(const float4*)(px + 4);
      }
      float vv[8] = {v0.x, v0.y, v0.z, v0.w, v1.x, v1.y, v1.z, v1.w};
      u16x8 hi, lo;
#pragma unroll
      for (int i = 0; i < 8; ++i) {
        u16 h = f2b(vv[i]);
        hi[i] = h;
        lo[i] = f2b(vv[i] - b2f(h));
      }
      *(u16x8*)((char*)L.st.xh + sxs) = hi;
      *(u16x8*)((char*)L.st.xl + sxs) = lo;
    }
#pragma unroll
    for (int li = 0; li < 2; ++li) {
      int i = tid + (li << 8);
      int col = i >> 2;
      int kb = (i & 3) << 4;
      u16x8 v = *(const u16x8*)((const char*)wt + (((size_t)(kt * 128 + col)) << 6) + kb);
      int sb = ((col << 6) + kb) ^ ((col & 7) << 4);
      *(u16x8*)((char*)L.st.wh + sb) = v;
    }
    __syncthreads();
    bf16x8 ah[4], al[4], bw[2];
#pragma unroll
    for (int mi = 0; mi < 4; ++mi) {
      int r = mi * 16 + frow;
      int sb = ((r << 6) + koff) ^ ((r & 7) << 4);
      ah[mi] = *(bf16x8*)((char*)L.st.xh + sb);
      al[mi] = *(bf16x8*)((char*)L.st.xl + sb);
    }
#pragma unroll
    for (int ni = 0; ni < 2; ++ni) {
      int c = (wave << 5) + ni * 16 + frow;
      int sb = ((c << 6) + koff) ^ ((c & 7) << 4);
      bw[ni] = *(bf16x8*)((char*)L.st.wh + sb);
    }
#pragma unroll
    for (int mi = 0; mi < 4; ++mi)
#pragma unroll
      for (int ni = 0; ni < 2; ++ni) {
        acc[mi][ni] = __builtin_amdgcn_mfma_f32_16x16x32_bf16(ah[mi], bw[ni], acc[mi][ni], 0, 0, 0);
        acc[mi][ni] = __builtin_amdgcn_mfma_f32_16x16x32_bf16(al[mi], bw[ni], acc[mi][ni], 0, 0, 0);
      }
    __syncthreads();
  }

#pragma unroll
  for (int mi = 0; mi < 4; ++mi)
#pragma unroll
    for (int ni = 0; ni < 2; ++ni) {
#pragma unroll
      for (int reg = 0; reg < 4; ++reg) {
        int row = mi * 16 + ((lane >> 4) << 2) + reg;
        int col = (wave << 5) + (ni << 4) + frow;
        L.cbuf[row * 132 + col] = acc[mi][ni][reg];
      }
    }
  __syncthreads();

  const int tc = tid & 31;
  const int tr = tid >> 5;
  const int head = tc >> 3;
  const int cb = (tc & 7) << 2;
  const float4 as4 = *(const float4*)&sA[head * 64 + cb];
  const float4 ad4 = *(const float4*)&sA[head * 64 + 32 + cb];
#pragma unroll
  for (int i = 0; i < 8; ++i) {
    int row = (tr << 3) + i;
    int grow = row0 + row;
    float4 v = *(const float4*)&L.cbuf[row * 132 + (tc << 2)];
    float ps = v.x * as4.x + v.y * as4.y + v.z * as4.z + v.w * as4.w;
    float pd = v.x * ad4.x + v.y * ad4.y + v.z * ad4.z + v.w * ad4.w;
    ps += __shfl_xor(ps, 1); ps += __shfl_xor(ps, 2); ps += __shfl_xor(ps, 4);
    pd += __shfl_xor(pd, 1); pd += __shfl_xor(pd, 2); pd += __shfl_xor(pd, 4);
    if (grow < NNODES) {
      u16 q[4] = {f2b(v.x), f2b(v.y), f2b(v.z), f2b(v.w)};
      // per-head plane layout: hb[head][node][32]
      *(ushort4*)&hb[((size_t)head * NNODES + grow) * 32 + cb] = *(ushort4*)q;
      if ((tc & 7) == 0) {
        nrec[(size_t)grow * NR + head] = ps;       // s_src
        nrec[(size_t)grow * NR + 4 + head] = pd;   // s_dst
      }
    }
  }
}

// ---- K2: chunked LDS histogram (u16-packed), per-edge local slot ----
__global__ __launch_bounds__(256) void k_chist(const int* __restrict__ rowi,
                                               u32* __restrict__ chunk_hist,
                                               u16* __restrict__ lslot) {
  __shared__ u32 lh[WORDS];  // 100 KB
  const int c = blockIdx.x;
  const int tid = threadIdx.x;
  for (int i = tid; i < WORDS; i += 256) lh[i] = 0;
  __syncthreads();
  const int base = c * CE;
  for (int i = tid; i < CE; i += 256) {
    int e = base + i;
    int r = rowi[e];
    u32 sh = (u32)(r & 1) << 4;
    u32 old = atomicAdd(&lh[r >> 1], 1u << sh);
    lslot[e] = (u16)((old >> sh) & 0xFFFFu);
  }
  __syncthreads();
  u32* dst = chunk_hist + (size_t)c * WORDS;
  for (int i = tid; i < WORDS; i += 256) dst[i] = lh[i];
}

// ---- K3: in-place column scan of chunk_hist over chunks; per-row totals ----
__global__ __launch_bounds__(256) void k_cscan(u32* __restrict__ chunk_hist,
                                               int* __restrict__ counts) {
  __shared__ u32 tile[NCHUNK][64];  // 32 KB
  const int w0 = blockIdx.x * 64;
  const int tid = threadIdx.x;
  for (int i = tid; i < NCHUNK * 64; i += 256) {
    int c = i >> 6, wl = i & 63;
    int w = w0 + wl;
    tile[c][wl] = (w < WORDS) ? chunk_hist[(size_t)c * WORDS + w] : 0u;
  }
  __syncthreads();
  if (tid < 64) {
    u32 slo = 0, shi = 0;
    for (int c = 0; c < NCHUNK; ++c) {
      u32 v = tile[c][tid];
      tile[c][tid] = slo | (shi << 16);
      slo += v & 0xFFFFu;
      shi += v >> 16;
    }
    int w = w0 + tid;
    if (w < WORDS) {
      int r = w << 1;
      if (r < NNODES) counts[r] = (int)slo;
      if (r + 1 < NNODES) counts[r + 1] = (int)shi;
    }
  }
  __syncthreads();
  for (int i = tid; i < NCHUNK * 64; i += 256) {
    int c = i >> 6, wl = i & 63;
    int w = w0 + wl;
    if (w < WORDS) chunk_hist[(size_t)c * WORDS + w] = tile[c][wl];
  }
}

// ---- K4a/b/c: full-GPU 3-phase exclusive scan of counts -> row_ptr ----
__global__ __launch_bounds__(256) void k_scan1(const int* __restrict__ counts,
                                               int* __restrict__ bsum) {
  int i = blockIdx.x * 256 + threadIdx.x;
  int v = (i < NNODES) ? counts[i] : 0;
#pragma unroll
  for (int m = 1; m < 64; m <<= 1) v += __shfl_xor(v, m);
  __shared__ int ws[4];
  if ((threadIdx.x & 63) == 0) ws[threadIdx.x >> 6] = v;
  __syncthreads();
  if (threadIdx.x == 0) bsum[blockIdx.x] = ws[0] + ws[1] + ws[2] + ws[3];
}

__global__ __launch_bounds__(256) void k_scan2(const int* __restrict__ bsum,
                                               int* __restrict__ boff) {
  __shared__ int s[256];
  int t = threadIdx.x;
  int v = (t < NSB) ? bsum[t] : 0;
  s[t] = v;
  __syncthreads();
  for (int off = 1; off < 256; off <<= 1) {
    int u = (t >= off) ? s[t - off] : 0;
    __syncthreads();
    s[t] += u;
    __syncthreads();
  }
  boff[t] = s[t] - v;
}

__global__ __launch_bounds__(256) void k_scan3(const int* __restrict__ counts,
                                               const int* __restrict__ boff,
                                               int* __restrict__ row_ptr) {
  __shared__ int s[256];
  int t = threadIdx.x;
  int i = blockIdx.x * 256 + t;
  int v = (i < NNODES) ? counts[i] : 0;
  s[t] = v;
  __syncthreads();
  for (int off = 1; off < 256; off <<= 1) {
    int u = (t >= off) ? s[t - off] : 0;
    __syncthreads();
    s[t] += u;
    __syncthreads();
  }
  if (i < NNODES) row_ptr[i] = boff[blockIdx.x] + s[t] - v;
  if (i == 0) row_ptr[NNODES] = NEDGES;
}

// ---- K5: atomic-free scatter of col (u16) into CSR — ONE 2B random store/edge ----
__global__ void k_scatter(const int* __restrict__ rowi, const int* __restrict__ coli,
                          const int* __restrict__ row_ptr,
                          const u32* __restrict__ chunk_hist,
                          const u16* __restrict__ lslot,
                          u16* __restrict__ col_csr) {
  int e = blockIdx.x * 256 + threadIdx.x;
  if (e >= NEDGES) return;
  int r = rowi[e];
  int c = e / CE;
  u32 word = chunk_hist[(size_t)c * WORDS + (r >> 1)];
  int off = (int)((word >> ((u32)(r & 1) << 4)) & 0xFFFFu);
  int pos = row_ptr[r] + off + (int)lslot[e];
  col_csr[pos] = (u16)coli[e];
}

// ---- K6: per-row wave softmax: writes mx/rden into nrec + bf16 an per-head planes ----
__global__ __launch_bounds__(256) void k_softmax(const u16* __restrict__ col_csr,
                                                 const int* __restrict__ row_ptr,
                                                 float* __restrict__ nrec,
                                                 u16* __restrict__ an_h) {
  const int wid = threadIdx.x >> 6;
  const int lane = threadIdx.x & 63;
  const int r = blockIdx.x * 4 + wid;
  if (r >= NNODES) return;
  const int p0 = row_ptr[r], p1 = row_ptr[r + 1];
  const int deg = p1 - p0;
  if (deg == 0) return;
  const float4 ss = *(const float4*)&nrec[(size_t)r * NR];
  const float NEG = -3.0e38f;

  if (deg <= 64) {
    float4 al = make_float4(NEG, NEG, NEG, NEG);
    if (lane < deg) {
      int c = col_csr[p0 + lane];
      float4 sd = *(const float4*)&nrec[(size_t)c * NR + 4];
      al.x = lrelu(ss.x + sd.x);
      al.y = lrelu(ss.y + sd.y);
      al.z = lrelu(ss.z + sd.z);
      al.w = lrelu(ss.w + sd.w);
    }
    float4 mx = al;
#pragma unroll
    for (int m = 1; m < 64; m <<= 1) {
      mx.x = fmaxf(mx.x, __shfl_xor(mx.x, m));
      mx.y = fmaxf(mx.y, __shfl_xor(mx.y, m));
      mx.z = fmaxf(mx.z, __shfl_xor(mx.z, m));
      mx.w = fmaxf(mx.w, __shfl_xor(mx.w, m));
    }
    float4 ex = make_float4(0.f, 0.f, 0.f, 0.f);
    if (lane < deg) {
      ex.x = __expf(al.x - mx.x);
      ex.y = __expf(al.y - mx.y);
      ex.z = __expf(al.z - mx.z);
      ex.w = __expf(al.w - mx.w);
    }
    float4 sm = ex;
#pragma unroll
    for (int m = 1; m < 64; m <<= 1) {
      sm.x += __shfl_xor(sm.x, m);
      sm.y += __shfl_xor(sm.y, m);
      sm.z += __shfl_xor(sm.z, m);
      sm.w += __shfl_xor(sm.w, m);
    }
    float4 rd = make_float4(1.f / sm.x, 1.f / sm.y, 1.f / sm.z, 1.f / sm.w);
    if (lane == 0) {
      *(float4*)&nrec[(size_t)r * NR + 8] = mx;
      *(float4*)&nrec[(size_t)r * NR + 12] = rd;
    }
    if (lane < deg) {
      int pos = p0 + lane;
      an_h[pos] = f2b(ex.x * rd.x);
      an_h[(size_t)NEDGES + pos] = f2b(ex.y * rd.y);
      an_h[(size_t)NEDGES * 2 + pos] = f2b(ex.z * rd.z);
      an_h[(size_t)NEDGES * 3 + pos] = f2b(ex.w * rd.w);
    }
  } else {
    float4 mx = make_float4(NEG, NEG, NEG, NEG);
    for (int p = p0 + lane; p < p1; p += 64) {
      int c = col_csr[p];
      float4 sd = *(const float4*)&nrec[(size_t)c * NR + 4];
      mx.x = fmaxf(mx.x, lrelu(ss.x + sd.x));
      mx.y = fmaxf(mx.y, lrelu(ss.y + sd.y));
      mx.z = fmaxf(mx.z, lrelu(ss.z + sd.z));
      mx.w = fmaxf(mx.w, lrelu(ss.w + sd.w));
    }
#pragma unroll
    for (int m = 1; m < 64; m <<= 1) {
      mx.x = fmaxf(mx.x, __shfl_xor(mx.x, m));
      mx.y = fmaxf(mx.y, __shfl_xor(mx.y, m));
      mx.z = fmaxf(mx.z, __shfl_xor(mx.z, m));
      mx.w = fmaxf(mx.w, __shfl_xor(mx.w, m));
    }
    float4 sm = make_float4(0.f, 0.f, 0.f, 0.f);
    for (int p = p0 + lane; p < p1; p += 64) {
      int c = col_csr[p];
      float4 sd = *(const float4*)&nrec[(size_t)c * NR + 4];
      sm.x += __expf(lrelu(ss.x + sd.x) - mx.x);
      sm.y += __expf(lrelu(ss.y + sd.y) - mx.y);
      sm.z += __expf(lrelu(ss.z + sd.z) - mx.z);
      sm.w += __expf(lrelu(ss.w + sd.w) - mx.w);
    }
#pragma unroll
    for (int m = 1; m < 64; m <<= 1) {
      sm.x += __shfl_xor(sm.x, m);
      sm.y += __shfl_xor(sm.y, m);
      sm.z += __shfl_xor(sm.z, m);
      sm.w += __shfl_xor(sm.w, m);
    }
    float4 rd = make_float4(1.f / sm.x, 1.f / sm.y, 1.f / sm.z, 1.f / sm.w);
    if (lane == 0) {
      *(float4*)&nrec[(size_t)r * NR + 8] = mx;
      *(float4*)&nrec[(size_t)r * NR + 12] = rd;
    }
    for (int p = p0 + lane; p < p1; p += 64) {
      int c = col_csr[p];
      float4 sd = *(const float4*)&nrec[(size_t)c * NR + 4];
      float4 ex;
      ex.x = __expf(lrelu(ss.x + sd.x) - mx.x) * rd.x;
      ex.y = __expf(lrelu(ss.y + sd.y) - mx.y) * rd.y;
      ex.z = __expf(lrelu(ss.z + sd.z) - mx.z) * rd.z;
      ex.w = __expf(lrelu(ss.w + sd.w) - mx.w) * rd.w;
      an_h[p] = f2b(ex.x);
      an_h[(size_t)NEDGES + p] = f2b(ex.y);
      an_h[(size_t)NEDGES * 2 + p] = f2b(ex.z);
      an_h[(size_t)NEDGES * 3 + p] = f2b(ex.w);
    }
  }
}

// ---- K7: alpha_norm in original edge order (coalesced float4 writes) ----
__global__ void k_alphaf(const int* __restrict__ rowi, const int* __restrict__ coli,
                         const float* __restrict__ nrec,
                         float* __restrict__ alpha_out) {
  int e = blockIdx.x * 256 + threadIdx.x;
  if (e >= NEDGES) return;
  int r = rowi[e], c = coli[e];
  const float* nr = &nrec[(size_t)r * NR];
  float4 ss = *(const float4*)(nr);
  float4 m4 = *(const float4*)(nr + 8);
  float4 rd = *(const float4*)(nr + 12);
  float4 sd = *(const float4*)&nrec[(size_t)c * NR + 4];
  float4 an;
  an.x = __expf(lrelu(ss.x + sd.x) - m4.x) * rd.x;
  an.y = __expf(lrelu(ss.y + sd.y) - m4.y) * rd.y;
  an.z = __expf(lrelu(ss.z + sd.z) - m4.z) * rd.z;
  an.w = __expf(lrelu(ss.w + sd.w) - m4.w) * rd.w;
  *(float4*)&alpha_out[(size_t)e * 4] = an;
}

// ---- K8: per-(row,head) wave aggregation. head = blockIdx&3 so each XCD
// (blockIdx%8 round-robin) touches ONE 3.2MB head plane -> L2-resident.
// 8 edges/wave-iter, 8 lanes/edge (8B of the 64B head row each). ----
__global__ __launch_bounds__(256) void k_aggr(const u16* __restrict__ col_csr,
                                              const int* __restrict__ row_ptr,
                                              const u16* __restrict__ an_h,
                                              const u16* __restrict__ hb,
                                              float* __restrict__ out_part) {
  const int wid = threadIdx.x >> 6;
  const int lane = threadIdx.x & 63;
  const int head = blockIdx.x & 3;
  const int r = (blockIdx.x >> 2) * 4 + wid;
  if (r >= NNODES) return;
  const int p0 = row_ptr[r], p1 = row_ptr[r + 1];
  const int eslot = lane >> 3;      // which of 8 in-flight edges
  const int cl = lane & 7;          // channel quad within the head row
  const u16* an_p = an_h + (size_t)head * NEDGES;
  const u16* hb_p = hb + (size_t)head * NNODES * 32;
  float a0 = 0.f, a1 = 0.f, a2 = 0.f, a3 = 0.f;

  int p = p0;
  for (; p + 32 <= p1; p += 32) {   // 4 groups of 8 edges
    int cs[4];
    float wv[4];
    u32 h0[4], h1[4];
#pragma unroll
    for (int i = 0; i < 4; ++i) {
      int idx = p + (i << 3) + eslot;
      cs[i] = col_csr[idx];
      wv[i] = b2f(an_p[idx]);
    }
#pragma unroll
    for (int i = 0; i < 4; ++i) {
      const u32* hp = (const u32*)(hb_p + ((size_t)cs[i] << 5) + (cl << 2));
      h0[i] = hp[0];
      h1[i] = hp[1];
    }
#pragma unroll
    for (int i = 0; i < 4; ++i) {
      a0 += wv[i] * __uint_as_float(h0[i] << 16);
      a1 += wv[i] * __uint_as_float(h0[i] & 0xFFFF0000u);
      a2 += wv[i] * __uint_as_float(h1[i] << 16);
      a3 += wv[i] * __uint_as_float(h1[i] & 0xFFFF0000u);
    }
  }
  for (; p < p1; p += 8) {          // remainder, mask inactive edge slots
    int idx = p + eslot;
    bool act = idx < p1;
    int c = act ? (int)col_csr[idx] : 0;
    float w = act ? b2f(an_p[idx]) : 0.f;
    const u32* hp = (const u32*)(hb_p + ((size_t)c << 5) + (cl << 2));
    u32 x0 = hp[0], x1 = hp[1];
    a0 += w * __uint_as_float(x0 << 16);
    a1 += w * __uint_as_float(x0 & 0xFFFF0000u);
    a2 += w * __uint_as_float(x1 << 16);
    a3 += w * __uint_as_float(x1 & 0xFFFF0000u);
  }
  // reduce across the 8 edge slots (lane bits 3,4,5)
  a0 += __shfl_xor(a0, 8);  a1 += __shfl_xor(a1, 8);
  a2 += __shfl_xor(a2, 8);  a3 += __shfl_xor(a3, 8);
  a0 += __shfl_xor(a0, 16); a1 += __shfl_xor(a1, 16);
  a2 += __shfl_xor(a2, 16); a3 += __shfl_xor(a3, 16);
  a0 += __shfl_xor(a0, 32); a1 += __shfl_xor(a1, 32);
  a2 += __shfl_xor(a2, 32); a3 += __shfl_xor(a3, 32);
  if (lane < 8) {
    float4 o = make_float4(a0 * 0.25f, a1 * 0.25f, a2 * 0.25f, a3 * 0.25f);
    *(float4*)&out_part[(((size_t)head * NNODES + r) << 5) + (lane << 2)] = o;
  }
}

// ---- K9: sum the 4 head planes into out_mean (0.25 already folded) ----
__global__ void k_redu(const float* __restrict__ out_part,
                       float* __restrict__ out_mean) {
  int i = blockIdx.x * 256 + threadIdx.x;   // float4 index
  if (i >= NNODES * 8) return;
  const float4* p0 = (const float4*)out_part;
  const size_t ps = (size_t)NNODES * 8;     // plane stride in float4
  float4 a = p0[i], b = p0[i + ps], c = p0[i + 2 * ps], d = p0[i + 3 * ps];
  float4 o = make_float4(a.x + b.x + c.x + d.x, a.y + b.y + c.y + d.y,
                         a.z + b.z + c.z + d.z, a.w + b.w + c.w + d.w);
  ((float4*)out_mean)[i] = o;
}

extern "C" void kernel_launch(void* const* d_in, const int* in_sizes, int n_in,
                              void* d_out, int out_size, void* d_ws, size_t ws_size,
                              hipStream_t stream) {
  const float* x = (const float*)d_in[0];
  const int* ei = (const int*)d_in[1];
  const float* W = (const float*)d_in[2];
  const float* attn = (const float*)d_in[3];
  const int* rowi = ei;
  const int* coli = ei + NEDGES;

  float* out_mean = (float*)d_out;
  float* alpha_out = (float*)d_out + (size_t)NNODES * 32;

  char* w = (char*)d_ws;
  u16* hb = (u16*)w;          w += (size_t)NNODES * HC * 2;       // 12.8 MB (4 head planes)
  u16* an_h = (u16*)w;        w += (size_t)NEDGES * 4 * 2;        // 12.8 MB (4 head planes)
  float* nrec = (float*)w;    w += (size_t)NNODES * NR * 4;       // 3.2 MB
  int* counts = (int*)w;      w += (size_t)NNODES * 4;
  int* bsum = (int*)w;        w += (size_t)256 * 4;
  int* boff = (int*)w;        w += (size_t)256 * 4;
  int* row_ptr = (int*)w;     w += (size_t)50016 * 4;
  u16* col_csr = (u16*)w;     w += (size_t)NEDGES * 2;            // 3.2 MB
  // region A: CSR-build scratch, dead after k_scatter; out_part overlays it
  char* regionA = w;
  u16* lslot = (u16*)regionA;                                     // 3.2 MB
  u32* chunk_hist = (u32*)(regionA + (size_t)NEDGES * 2);         // 12.8 MB
  u16* wt = (u16*)(regionA + (size_t)NEDGES * 2 + (size_t)NCHUNK * WORDS * 4);  // 64 KB
  float* out_part = (float*)regionA;                              // 25.6 MB (4 planes)

  k_wprep<<<(IN_CH * HC + 255) / 256, 256, 0, stream>>>(W, wt);
  k_gemm<<<(NNODES + 63) / 64, 256, 0, stream>>>(x, wt, attn, hb, nrec);
  k_chist<<<NCHUNK, 256, 0, stream>>>(rowi, chunk_hist, lslot);
  k_cscan<<<(WORDS + 63) / 64, 256, 0, stream>>>(chunk_hist, counts);
  k_scan1<<<NSB, 256, 0, stream>>>(counts, bsum);
  k_scan2<<<1, 256, 0, stream>>>(bsum, boff);
  k_scan3<<<NSB, 256, 0, stream>>>(counts, boff, row_ptr);
  k_scatter<<<(NEDGES + 255) / 256, 256, 0, stream>>>(rowi, coli, row_ptr, chunk_hist, lslot, col_csr);
  k_softmax<<<(NNODES + 3) / 4, 256, 0, stream>>>(col_csr, row_ptr, nrec, an_h);
  k_alphaf<<<(NEDGES + 255) / 256, 256, 0, stream>>>(rowi, coli, nrec, alpha_out);
  k_aggr<<<((NNODES + 3) / 4) * 4, 256, 0, stream>>>(col_csr, row_ptr, an_h, hb, out_part);
  k_redu<<<(NNODES * 8 + 255) / 256, 256, 0, stream>>>(out_part, out_mean);
}

// Round 10
// 247.369 us; speedup vs baseline: 1.0980x; 1.0980x over previous
//
#include <hip/hip_runtime.h>

#define NNODES 50000
#define NEDGES 1600000
#define IN_CH 256
#define HEADS 4
#define OUT_CH 32
#define HC 128                       // HEADS*OUT_CH
#define NSB ((NNODES + 255) / 256)   // 196 scan blocks
#define NCHUNK 128
#define CE 12500                     // edges per chunk; 128*12500 == NEDGES
#define WORDS 25000                  // u32 words per chunk hist (2 u16 bins/word)

typedef unsigned int u32;
typedef unsigned short u16;
typedef short bf16x8 __attribute__((ext_vector_type(8)));   // 8 bf16 in 4 VGPRs
typedef u16 u16x8 __attribute__((ext_vector_type(8)));
typedef float f32x4 __attribute__((ext_vector_type(4)));

__device__ __forceinline__ float b2f(u16 s) { return __uint_as_float(((u32)s) << 16); }
__device__ __forceinline__ u16 f2b(float f) {
  u32 u = __float_as_uint(f);
  u32 r = (u + 0x7FFFu + ((u >> 16) & 1u)) >> 16;
  return (u16)r;
}
__device__ __forceinline__ float lrelu(float v) { return v >= 0.f ? v : 0.2f * v; }

// node record layout (16 floats = 64B): [0:4)=s_src, [4:8)=s_dst, [8:12)=mx, [12:16)=rden
#define NR 16

// ---- K0: W (256x128 f32) -> bf16, transposed+tiled: wt[((kt*128+n)*32+kk)] ----
__global__ __launch_bounds__(256) void k_wprep(const float* __restrict__ W,
                                               u16* __restrict__ wt) {
  int i = blockIdx.x * 256 + threadIdx.x;   // 0..32767
  if (i >= IN_CH * HC) return;
  int kk = i & 31;
  int n = (i >> 5) & 127;
  int kt = i >> 12;
  wt[i] = f2b(W[(size_t)(kt * 32 + kk) * HC + n]);
}

// ---- K1: h = x @ W via bf16 MFMA (x split hi+lo), fused bf16-h store + scores ----
__global__ __launch_bounds__(256) void k_gemm(const float* __restrict__ x,
                                              const u16* __restrict__ wt,
                                              const float* __restrict__ attn,
                                              u16* __restrict__ hb,
                                              float* __restrict__ nrec) {
  __shared__ union {
    struct {
      u16 xh[64 * 32];    // 4 KB, XOR-swizzled
      u16 xl[64 * 32];    // 4 KB
      u16 wh[128 * 32];   // 8 KB
    } st;
    float cbuf[64 * 132]; // 33.8 KB (row stride 132 f32)
  } L;
  __shared__ float sA[256];
  const int tid = threadIdx.x;
  const int wave = tid >> 6;
  const int lane = tid & 63;
  const int row0 = blockIdx.x * 64;
  sA[tid] = attn[tid];

  f32x4 acc[4][2] = {};           // [mi 16-row frag][ni 16-col frag]
  const int frow = lane & 15;
  const int koff = (lane >> 4) << 4;

  const int sr = tid >> 2;
  const int skc = (tid & 3) << 3;
  const int sgrow = row0 + sr;
  const int sxb = (sr << 6) + (skc << 1);
  const int sxs = sxb ^ ((sr & 7) << 4);

  for (int kt = 0; kt < 8; ++kt) {
    {
      float4 v0 = make_float4(0.f, 0.f, 0.f, 0.f), v1 = v0;
      if (sgrow < NNODES) {
        const float* px = &x[(size_t)sgrow * IN_CH + kt * 32 + skc];
        v0 = *(const float4*)px;
        v1 = *(const float4*)(px + 4);
      }
      float vv[8] = {v0.x, v0.y, v0.z, v0.w, v1.x, v1.y, v1.z, v1.w};
      u16x8 hi, lo;
#pragma unroll
      for (int i = 0; i < 8; ++i) {
        u16 h = f2b(vv[i]);
        hi[i] = h;
        lo[i] = f2b(vv[i] - b2f(h));
      }
      *(u16x8*)((char*)L.st.xh + sxs) = hi;
      *(u16x8*)((char*)L.st.xl + sxs) = lo;
    }
#pragma unroll
    for (int li = 0; li < 2; ++li) {
      int i = tid + (li << 8);
      int col = i >> 2;
      int kb = (i & 3) << 4;
      u16x8 v = *(const u16x8*)((const char*)wt + (((size_t)(kt * 128 + col)) << 6) + kb);
      int sb = ((col << 6) + kb) ^ ((col & 7) << 4);
      *(u16x8*)((char*)L.st.wh + sb) = v;
    }
    __syncthreads();
    bf16x8 ah[4], al[4], bw[2];
#pragma unroll
    for (int mi = 0; mi < 4; ++mi) {
      int r = mi * 16 + frow;
      int sb = ((r << 6) + koff) ^ ((r & 7) << 4);
      ah[mi] = *(bf16x8*)((char*)L.st.xh + sb);
      al[mi] = *(bf16x8*)((char*)L.st.xl + sb);
    }
#pragma unroll
    for (int ni = 0; ni < 2; ++ni) {
      int c = (wave << 5) + ni * 16 + frow;
      int sb = ((c << 6) + koff) ^ ((c & 7) << 4);
      bw[ni] = *(bf16x8*)((char*)L.st.wh + sb);
    }
#pragma unroll
    for (int mi = 0; mi < 4; ++mi)
#pragma unroll
      for (int ni = 0; ni < 2; ++ni) {
        acc[mi][ni] = __builtin_amdgcn_mfma_f32_16x16x32_bf16(ah[mi], bw[ni], acc[mi][ni], 0, 0, 0);
        acc[mi][ni] = __builtin_amdgcn_mfma_f32_16x16x32_bf16(al[mi], bw[ni], acc[mi][ni], 0, 0, 0);
      }
    __syncthreads();
  }

#pragma unroll
  for (int mi = 0; mi < 4; ++mi)
#pragma unroll
    for (int ni = 0; ni < 2; ++ni) {
#pragma unroll
      for (int reg = 0; reg < 4; ++reg) {
        int row = mi * 16 + ((lane >> 4) << 2) + reg;
        int col = (wave << 5) + (ni << 4) + frow;
        L.cbuf[row * 132 + col] = acc[mi][ni][reg];
      }
    }
  __syncthreads();

  const int tc = tid & 31;
  const int tr = tid >> 5;
  const int head = tc >> 3;
  const int cb = (tc & 7) << 2;
  const float4 as4 = *(const float4*)&sA[head * 64 + cb];
  const float4 ad4 = *(const float4*)&sA[head * 64 + 32 + cb];
#pragma unroll
  for (int i = 0; i < 8; ++i) {
    int row = (tr << 3) + i;
    int grow = row0 + row;
    float4 v = *(const float4*)&L.cbuf[row * 132 + (tc << 2)];
    float ps = v.x * as4.x + v.y * as4.y + v.z * as4.z + v.w * as4.w;
    float pd = v.x * ad4.x + v.y * ad4.y + v.z * ad4.z + v.w * ad4.w;
    ps += __shfl_xor(ps, 1); ps += __shfl_xor(ps, 2); ps += __shfl_xor(ps, 4);
    pd += __shfl_xor(pd, 1); pd += __shfl_xor(pd, 2); pd += __shfl_xor(pd, 4);
    if (grow < NNODES) {
      u16 q[4] = {f2b(v.x), f2b(v.y), f2b(v.z), f2b(v.w)};
      *(ushort4*)&hb[(size_t)grow * HC + (tc << 2)] = *(ushort4*)q;
      if ((tc & 7) == 0) {
        nrec[(size_t)grow * NR + head] = ps;       // s_src
        nrec[(size_t)grow * NR + 4 + head] = pd;   // s_dst
      }
    }
  }
}

// ---- K2: chunked LDS histogram (u16-packed), per-edge local slot ----
__global__ __launch_bounds__(256) void k_chist(const int* __restrict__ rowi,
                                               u32* __restrict__ chunk_hist,
                                               u16* __restrict__ lslot) {
  __shared__ u32 lh[WORDS];  // 100 KB
  const int c = blockIdx.x;
  const int tid = threadIdx.x;
  for (int i = tid; i < WORDS; i += 256) lh[i] = 0;
  __syncthreads();
  const int base = c * CE;
  for (int i = tid; i < CE; i += 256) {
    int e = base + i;
    int r = rowi[e];
    u32 sh = (u32)(r & 1) << 4;
    u32 old = atomicAdd(&lh[r >> 1], 1u << sh);
    lslot[e] = (u16)((old >> sh) & 0xFFFFu);
  }
  __syncthreads();
  u32* dst = chunk_hist + (size_t)c * WORDS;
  for (int i = tid; i < WORDS; i += 256) dst[i] = lh[i];
}

// ---- K3: in-place column scan of chunk_hist over chunks; per-row totals ----
__global__ __launch_bounds__(256) void k_cscan(u32* __restrict__ chunk_hist,
                                               int* __restrict__ counts) {
  __shared__ u32 tile[NCHUNK][64];  // 32 KB
  const int w0 = blockIdx.x * 64;
  const int tid = threadIdx.x;
  for (int i = tid; i < NCHUNK * 64; i += 256) {
    int c = i >> 6, wl = i & 63;
    int w = w0 + wl;
    tile[c][wl] = (w < WORDS) ? chunk_hist[(size_t)c * WORDS + w] : 0u;
  }
  __syncthreads();
  if (tid < 64) {
    u32 slo = 0, shi = 0;
    for (int c = 0; c < NCHUNK; ++c) {
      u32 v = tile[c][tid];
      tile[c][tid] = slo | (shi << 16);
      slo += v & 0xFFFFu;
      shi += v >> 16;
    }
    int w = w0 + tid;
    if (w < WORDS) {
      int r = w << 1;
      if (r < NNODES) counts[r] = (int)slo;
      if (r + 1 < NNODES) counts[r + 1] = (int)shi;
    }
  }
  __syncthreads();
  for (int i = tid; i < NCHUNK * 64; i += 256) {
    int c = i >> 6, wl = i & 63;
    int w = w0 + wl;
    if (w < WORDS) chunk_hist[(size_t)c * WORDS + w] = tile[c][wl];
  }
}

// ---- K4a/b/c: full-GPU 3-phase exclusive scan of counts -> row_ptr ----
__global__ __launch_bounds__(256) void k_scan1(const int* __restrict__ counts,
                                               int* __restrict__ bsum) {
  int i = blockIdx.x * 256 + threadIdx.x;
  int v = (i < NNODES) ? counts[i] : 0;
#pragma unroll
  for (int m = 1; m < 64; m <<= 1) v += __shfl_xor(v, m);
  __shared__ int ws[4];
  if ((threadIdx.x & 63) == 0) ws[threadIdx.x >> 6] = v;
  __syncthreads();
  if (threadIdx.x == 0) bsum[blockIdx.x] = ws[0] + ws[1] + ws[2] + ws[3];
}

__global__ __launch_bounds__(256) void k_scan2(const int* __restrict__ bsum,
                                               int* __restrict__ boff) {
  __shared__ int s[256];
  int t = threadIdx.x;
  int v = (t < NSB) ? bsum[t] : 0;
  s[t] = v;
  __syncthreads();
  for (int off = 1; off < 256; off <<= 1) {
    int u = (t >= off) ? s[t - off] : 0;
    __syncthreads();
    s[t] += u;
    __syncthreads();
  }
  boff[t] = s[t] - v;
}

__global__ __launch_bounds__(256) void k_scan3(const int* __restrict__ counts,
                                               const int* __restrict__ boff,
                                               int* __restrict__ row_ptr) {
  __shared__ int s[256];
  int t = threadIdx.x;
  int i = blockIdx.x * 256 + t;
  int v = (i < NNODES) ? counts[i] : 0;
  s[t] = v;
  __syncthreads();
  for (int off = 1; off < 256; off <<= 1) {
    int u = (t >= off) ? s[t - off] : 0;
    __syncthreads();
    s[t] += u;
    __syncthreads();
  }
  if (i < NNODES) row_ptr[i] = boff[blockIdx.x] + s[t] - v;
  if (i == 0) row_ptr[NNODES] = NEDGES;
}

// ---- K5: atomic-free scatter of col (u16) into CSR — ONE 2B random store/edge ----
__global__ void k_scatter(const int* __restrict__ rowi, const int* __restrict__ coli,
                          const int* __restrict__ row_ptr,
                          const u32* __restrict__ chunk_hist,
                          const u16* __restrict__ lslot,
                          u16* __restrict__ col_csr) {
  int e = blockIdx.x * 256 + threadIdx.x;
  if (e >= NEDGES) return;
  int r = rowi[e];
  int c = e / CE;
  u32 word = chunk_hist[(size_t)c * WORDS + (r >> 1)];
  int off = (int)((word >> ((u32)(r & 1) << 4)) & 0xFFFFu);
  int pos = row_ptr[r] + off + (int)lslot[e];
  col_csr[pos] = (u16)coli[e];
}

// ---- K6: per-row wave softmax: writes mx/rden into nrec + bf16 an in CSR order ----
__global__ __launch_bounds__(256) void k_softmax(const u16* __restrict__ col_csr,
                                                 const int* __restrict__ row_ptr,
                                                 float* __restrict__ nrec,
                                                 u16* __restrict__ an16) {
  const int wid = threadIdx.x >> 6;
  const int lane = threadIdx.x & 63;
  const int r = blockIdx.x * 4 + wid;
  if (r >= NNODES) return;
  const int p0 = row_ptr[r], p1 = row_ptr[r + 1];
  const int deg = p1 - p0;
  if (deg == 0) return;
  const float4 ss = *(const float4*)&nrec[(size_t)r * NR];
  const float NEG = -3.0e38f;

  if (deg <= 64) {
    float4 al = make_float4(NEG, NEG, NEG, NEG);
    if (lane < deg) {
      int c = col_csr[p0 + lane];
      float4 sd = *(const float4*)&nrec[(size_t)c * NR + 4];
      al.x = lrelu(ss.x + sd.x);
      al.y = lrelu(ss.y + sd.y);
      al.z = lrelu(ss.z + sd.z);
      al.w = lrelu(ss.w + sd.w);
    }
    float4 mx = al;
#pragma unroll
    for (int m = 1; m < 64; m <<= 1) {
      mx.x = fmaxf(mx.x, __shfl_xor(mx.x, m));
      mx.y = fmaxf(mx.y, __shfl_xor(mx.y, m));
      mx.z = fmaxf(mx.z, __shfl_xor(mx.z, m));
      mx.w = fmaxf(mx.w, __shfl_xor(mx.w, m));
    }
    float4 ex = make_float4(0.f, 0.f, 0.f, 0.f);
    if (lane < deg) {
      ex.x = __expf(al.x - mx.x);
      ex.y = __expf(al.y - mx.y);
      ex.z = __expf(al.z - mx.z);
      ex.w = __expf(al.w - mx.w);
    }
    float4 sm = ex;
#pragma unroll
    for (int m = 1; m < 64; m <<= 1) {
      sm.x += __shfl_xor(sm.x, m);
      sm.y += __shfl_xor(sm.y, m);
      sm.z += __shfl_xor(sm.z, m);
      sm.w += __shfl_xor(sm.w, m);
    }
    float4 rd = make_float4(1.f / sm.x, 1.f / sm.y, 1.f / sm.z, 1.f / sm.w);
    if (lane == 0) {
      *(float4*)&nrec[(size_t)r * NR + 8] = mx;
      *(float4*)&nrec[(size_t)r * NR + 12] = rd;
    }
    if (lane < deg) {
      u16 q[4] = {f2b(ex.x * rd.x), f2b(ex.y * rd.y), f2b(ex.z * rd.z), f2b(ex.w * rd.w)};
      *(ushort4*)&an16[(size_t)(p0 + lane) * 4] = *(ushort4*)q;
    }
  } else {
    float4 mx = make_float4(NEG, NEG, NEG, NEG);
    for (int p = p0 + lane; p < p1; p += 64) {
      int c = col_csr[p];
      float4 sd = *(const float4*)&nrec[(size_t)c * NR + 4];
      mx.x = fmaxf(mx.x, lrelu(ss.x + sd.x));
      mx.y = fmaxf(mx.y, lrelu(ss.y + sd.y));
      mx.z = fmaxf(mx.z, lrelu(ss.z + sd.z));
      mx.w = fmaxf(mx.w, lrelu(ss.w + sd.w));
    }
#pragma unroll
    for (int m = 1; m < 64; m <<= 1) {
      mx.x = fmaxf(mx.x, __shfl_xor(mx.x, m));
      mx.y = fmaxf(mx.y, __shfl_xor(mx.y, m));
      mx.z = fmaxf(mx.z, __shfl_xor(mx.z, m));
      mx.w = fmaxf(mx.w, __shfl_xor(mx.w, m));
    }
    float4 sm = make_float4(0.f, 0.f, 0.f, 0.f);
    for (int p = p0 + lane; p < p1; p += 64) {
      int c = col_csr[p];
      float4 sd = *(const float4*)&nrec[(size_t)c * NR + 4];
      sm.x += __expf(lrelu(ss.x + sd.x) - mx.x);
      sm.y += __expf(lrelu(ss.y + sd.y) - mx.y);
      sm.z += __expf(lrelu(ss.z + sd.z) - mx.z);
      sm.w += __expf(lrelu(ss.w + sd.w) - mx.w);
    }
#pragma unroll
    for (int m = 1; m < 64; m <<= 1) {
      sm.x += __shfl_xor(sm.x, m);
      sm.y += __shfl_xor(sm.y, m);
      sm.z += __shfl_xor(sm.z, m);
      sm.w += __shfl_xor(sm.w, m);
    }
    float4 rd = make_float4(1.f / sm.x, 1.f / sm.y, 1.f / sm.z, 1.f / sm.w);
    if (lane == 0) {
      *(float4*)&nrec[(size_t)r * NR + 8] = mx;
      *(float4*)&nrec[(size_t)r * NR + 12] = rd;
    }
    for (int p = p0 + lane; p < p1; p += 64) {
      int c = col_csr[p];
      float4 sd = *(const float4*)&nrec[(size_t)c * NR + 4];
      float4 ex;
      ex.x = __expf(lrelu(ss.x + sd.x) - mx.x) * rd.x;
      ex.y = __expf(lrelu(ss.y + sd.y) - mx.y) * rd.y;
      ex.z = __expf(lrelu(ss.z + sd.z) - mx.z) * rd.z;
      ex.w = __expf(lrelu(ss.w + sd.w) - mx.w) * rd.w;
      u16 q[4] = {f2b(ex.x), f2b(ex.y), f2b(ex.z), f2b(ex.w)};
      *(ushort4*)&an16[(size_t)p * 4] = *(ushort4*)q;
    }
  }
}

// ---- K7: alpha_norm in original edge order (coalesced float4 writes);
//      r-side tables (ss,mx,rd) live in one 64B nrec line ----
__global__ void k_alphaf(const int* __restrict__ rowi, const int* __restrict__ coli,
                         const float* __restrict__ nrec,
                         float* __restrict__ alpha_out) {
  int e = blockIdx.x * 256 + threadIdx.x;
  if (e >= NEDGES) return;
  int r = rowi[e], c = coli[e];
  const float* nr = &nrec[(size_t)r * NR];
  float4 ss = *(const float4*)(nr);
  float4 m4 = *(const float4*)(nr + 8);
  float4 rd = *(const float4*)(nr + 12);
  float4 sd = *(const float4*)&nrec[(size_t)c * NR + 4];
  float4 an;
  an.x = __expf(lrelu(ss.x + sd.x) - m4.x) * rd.x;
  an.y = __expf(lrelu(ss.y + sd.y) - m4.y) * rd.y;
  an.z = __expf(lrelu(ss.z + sd.z) - m4.z) * rd.z;
  an.w = __expf(lrelu(ss.w + sd.w) - m4.w) * rd.w;
  *(float4*)&alpha_out[(size_t)e * 4] = an;
}

// ---- K8: per-row wave aggregation, 16-deep gather pipeline + masked 16-wide tail
// (no serial remainder). Lane covers 2 channels of the 128-ch interleaved h row. ----
__global__ __launch_bounds__(256) void k_aggr(const u16* __restrict__ col_csr,
                                              const int* __restrict__ row_ptr,
                                              const u16* __restrict__ an16,
                                              const u16* __restrict__ hb,
                                              float* __restrict__ out_mean) {
  const int wid = threadIdx.x >> 6;
  const int lane = threadIdx.x & 63;
  const int r = blockIdx.x * 4 + wid;
  if (r >= NNODES) return;
  const int p0 = row_ptr[r], p1 = row_ptr[r + 1];
  const int hd = lane >> 4;
  const int ch = lane << 1;
  float acc0 = 0.f, acc1 = 0.f;

  int p = p0;
  for (; p + 16 <= p1; p += 16) {   // full 16-deep tier
    int cs[16];
    float ws[16];
    u32 hv[16];
#pragma unroll
    for (int i = 0; i < 16; ++i) cs[i] = col_csr[p + i];
#pragma unroll
    for (int i = 0; i < 16; ++i) ws[i] = b2f(an16[(size_t)(p + i) * 4 + hd]);
#pragma unroll
    for (int i = 0; i < 16; ++i) hv[i] = *(const u32*)&hb[(size_t)cs[i] * HC + ch];
#pragma unroll
    for (int i = 0; i < 16; ++i) {
      acc0 += ws[i] * b2f((u16)(hv[i] & 0xFFFFu));
      acc1 += ws[i] * b2f((u16)(hv[i] >> 16));
    }
  }
  if (p < p1) {                     // single masked 16-wide tail
    int cs[16];
    float ws[16];
    u32 hv[16];
#pragma unroll
    for (int i = 0; i < 16; ++i) {
      bool act = (p + i) < p1;
      cs[i] = act ? (int)col_csr[p + i] : 0;
      ws[i] = act ? b2f(an16[(size_t)(p + i) * 4 + hd]) : 0.f;
    }
#pragma unroll
    for (int i = 0; i < 16; ++i) hv[i] = *(const u32*)&hb[(size_t)cs[i] * HC + ch];
#pragma unroll
    for (int i = 0; i < 16; ++i) {
      acc0 += ws[i] * b2f((u16)(hv[i] & 0xFFFFu));
      acc1 += ws[i] * b2f((u16)(hv[i] >> 16));
    }
  }
  acc0 += __shfl_xor(acc0, 16);
  acc0 += __shfl_xor(acc0, 32);
  acc1 += __shfl_xor(acc1, 16);
  acc1 += __shfl_xor(acc1, 32);
  if (lane < 16) {
    float2 o = make_float2(acc0 * 0.25f, acc1 * 0.25f);
    *(float2*)&out_mean[(size_t)r * 32 + (lane << 1)] = o;
  }
}

extern "C" void kernel_launch(void* const* d_in, const int* in_sizes, int n_in,
                              void* d_out, int out_size, void* d_ws, size_t ws_size,
                              hipStream_t stream) {
  const float* x = (const float*)d_in[0];
  const int* ei = (const int*)d_in[1];
  const float* W = (const float*)d_in[2];
  const float* attn = (const float*)d_in[3];
  const int* rowi = ei;
  const int* coli = ei + NEDGES;

  float* out_mean = (float*)d_out;
  float* alpha_out = (float*)d_out + (size_t)NNODES * 32;

  char* w = (char*)d_ws;
  u16* hb = (u16*)w;          w += (size_t)NNODES * HC * 2;       // 12.8 MB
  u16* an16 = (u16*)w;        w += (size_t)NEDGES * 4 * 2;        // 12.8 MB
  float* nrec = (float*)w;    w += (size_t)NNODES * NR * 4;       // 3.2 MB (64B/node)
  int* counts = (int*)w;      w += (size_t)NNODES * 4;
  int* bsum = (int*)w;        w += (size_t)256 * 4;
  int* boff = (int*)w;        w += (size_t)256 * 4;
  int* row_ptr = (int*)w;     w += (size_t)50016 * 4;
  u16* lslot = (u16*)w;       w += (size_t)NEDGES * 2;            // 3.2 MB
  u16* col_csr = (u16*)w;     w += (size_t)NEDGES * 2;            // 3.2 MB
  u32* chunk_hist = (u32*)w;  w += (size_t)NCHUNK * WORDS * 4;    // 12.8 MB
  u16* wt = (u16*)w;          w += (size_t)IN_CH * HC * 2;        // 64 KB

  k_wprep<<<(IN_CH * HC + 255) / 256, 256, 0, stream>>>(W, wt);
  k_gemm<<<(NNODES + 63) / 64, 256, 0, stream>>>(x, wt, attn, hb, nrec);
  k_chist<<<NCHUNK, 256, 0, stream>>>(rowi, chunk_hist, lslot);
  k_cscan<<<(WORDS + 63) / 64, 256, 0, stream>>>(chunk_hist, counts);
  k_scan1<<<NSB, 256, 0, stream>>>(counts, bsum);
  k_scan2<<<1, 256, 0, stream>>>(bsum, boff);
  k_scan3<<<NSB, 256, 0, stream>>>(counts, boff, row_ptr);
  k_scatter<<<(NEDGES + 255) / 256, 256, 0, stream>>>(rowi, coli, row_ptr, chunk_hist, lslot, col_csr);
  k_softmax<<<(NNODES + 3) / 4, 256, 0, stream>>>(col_csr, row_ptr, nrec, an16);
  k_alphaf<<<(NEDGES + 255) / 256, 256, 0, stream>>>(rowi, coli, nrec, alpha_out);
  k_aggr<<<(NNODES + 3) / 4, 256, 0, stream>>>(col_csr, row_ptr, an16, hb, out_mean);
}

// Round 11
// 225.505 us; speedup vs baseline: 1.2045x; 1.0970x over previous
//
#include <hip/hip_runtime.h>

#define NNODES 50000
#define NEDGES 1600000
#define IN_CH 256
#define HEADS 4
#define OUT_CH 32
#define HC 128                       // HEADS*OUT_CH
#define NSB ((NNODES + 255) / 256)   // 196 scan blocks
#define NCHUNK 128
#define CE 12500                     // edges per chunk; 128*12500 == NEDGES
#define WORDS 25000                  // u32 words per chunk hist (2 u16 bins/word)

typedef unsigned int u32;
typedef unsigned short u16;
typedef short bf16x8 __attribute__((ext_vector_type(8)));   // 8 bf16 in 4 VGPRs
typedef u16 u16x8 __attribute__((ext_vector_type(8)));
typedef float f32x4 __attribute__((ext_vector_type(4)));

__device__ __forceinline__ float b2f(u16 s) { return __uint_as_float(((u32)s) << 16); }
__device__ __forceinline__ u16 f2b(float f) {
  u32 u = __float_as_uint(f);
  u32 r = (u + 0x7FFFu + ((u >> 16) & 1u)) >> 16;
  return (u16)r;
}
__device__ __forceinline__ float lrelu(float v) { return v >= 0.f ? v : 0.2f * v; }

// node record layout (16 floats = 64B): [0:4)=s_src, [4:8)=s_dst, [8:12)=mx, [12:16)=rden
#define NR 16

// ---- K0: W (256x128 f32) -> bf16, transposed+tiled: wt[((kt*128+n)*32+kk)] ----
__global__ __launch_bounds__(256) void k_wprep(const float* __restrict__ W,
                                               u16* __restrict__ wt) {
  int i = blockIdx.x * 256 + threadIdx.x;   // 0..32767
  if (i >= IN_CH * HC) return;
  int kk = i & 31;
  int n = (i >> 5) & 127;
  int kt = i >> 12;
  wt[i] = f2b(W[(size_t)(kt * 32 + kk) * HC + n]);
}

// ---- K1: h = x @ W via bf16 MFMA (x split hi+lo), fused bf16-h store + scores ----
__global__ __launch_bounds__(256) void k_gemm(const float* __restrict__ x,
                                              const u16* __restrict__ wt,
                                              const float* __restrict__ attn,
                                              u16* __restrict__ hb,
                                              float* __restrict__ nrec) {
  __shared__ union {
    struct {
      u16 xh[64 * 32];    // 4 KB, XOR-swizzled
      u16 xl[64 * 32];    // 4 KB
      u16 wh[128 * 32];   // 8 KB
    } st;
    float cbuf[64 * 132]; // 33.8 KB (row stride 132 f32)
  } L;
  __shared__ float sA[256];
  const int tid = threadIdx.x;
  const int wave = tid >> 6;
  const int lane = tid & 63;
  const int row0 = blockIdx.x * 64;
  sA[tid] = attn[tid];

  f32x4 acc[4][2] = {};           // [mi 16-row frag][ni 16-col frag]
  const int frow = lane & 15;
  const int koff = (lane >> 4) << 4;

  const int sr = tid >> 2;
  const int skc = (tid & 3) << 3;
  const int sgrow = row0 + sr;
  const int sxb = (sr << 6) + (skc << 1);
  const int sxs = sxb ^ ((sr & 7) << 4);

  for (int kt = 0; kt < 8; ++kt) {
    {
      float4 v0 = make_float4(0.f, 0.f, 0.f, 0.f), v1 = v0;
      if (sgrow < NNODES) {
        const float* px = &x[(size_t)sgrow * IN_CH + kt * 32 + skc];
        v0 = *(const float4*)px;
        v1 = *(const float4*)(px + 4);
      }
      float vv[8] = {v0.x, v0.y, v0.z, v0.w, v1.x, v1.y, v1.z, v1.w};
      u16x8 hi, lo;
#pragma unroll
      for (int i = 0; i < 8; ++i) {
        u16 h = f2b(vv[i]);
        hi[i] = h;
        lo[i] = f2b(vv[i] - b2f(h));
      }
      *(u16x8*)((char*)L.st.xh + sxs) = hi;
      *(u16x8*)((char*)L.st.xl + sxs) = lo;
    }
#pragma unroll
    for (int li = 0; li < 2; ++li) {
      int i = tid + (li << 8);
      int col = i >> 2;
      int kb = (i & 3) << 4;
      u16x8 v = *(const u16x8*)((const char*)wt + (((size_t)(kt * 128 + col)) << 6) + kb);
      int sb = ((col << 6) + kb) ^ ((col & 7) << 4);
      *(u16x8*)((char*)L.st.wh + sb) = v;
    }
    __syncthreads();
    bf16x8 ah[4], al[4], bw[2];
#pragma unroll
    for (int mi = 0; mi < 4; ++mi) {
      int r = mi * 16 + frow;
      int sb = ((r << 6) + koff) ^ ((r & 7) << 4);
      ah[mi] = *(bf16x8*)((char*)L.st.xh + sb);
      al[mi] = *(bf16x8*)((char*)L.st.xl + sb);
    }
#pragma unroll
    for (int ni = 0; ni < 2; ++ni) {
      int c = (wave << 5) + ni * 16 + frow;
      int sb = ((c << 6) + koff) ^ ((c & 7) << 4);
      bw[ni] = *(bf16x8*)((char*)L.st.wh + sb);
    }
#pragma unroll
    for (int mi = 0; mi < 4; ++mi)
#pragma unroll
      for (int ni = 0; ni < 2; ++ni) {
        acc[mi][ni] = __builtin_amdgcn_mfma_f32_16x16x32_bf16(ah[mi], bw[ni], acc[mi][ni], 0, 0, 0);
        acc[mi][ni] = __builtin_amdgcn_mfma_f32_16x16x32_bf16(al[mi], bw[ni], acc[mi][ni], 0, 0, 0);
      }
    __syncthreads();
  }

#pragma unroll
  for (int mi = 0; mi < 4; ++mi)
#pragma unroll
    for (int ni = 0; ni < 2; ++ni) {
#pragma unroll
      for (int reg = 0; reg < 4; ++reg) {
        int row = mi * 16 + ((lane >> 4) << 2) + reg;
        int col = (wave << 5) + (ni << 4) + frow;
        L.cbuf[row * 132 + col] = acc[mi][ni][reg];
      }
    }
  __syncthreads();

  const int tc = tid & 31;
  const int tr = tid >> 5;
  const int head = tc >> 3;
  const int cb = (tc & 7) << 2;
  const float4 as4 = *(const float4*)&sA[head * 64 + cb];
  const float4 ad4 = *(const float4*)&sA[head * 64 + 32 + cb];
#pragma unroll
  for (int i = 0; i < 8; ++i) {
    int row = (tr << 3) + i;
    int grow = row0 + row;
    float4 v = *(const float4*)&L.cbuf[row * 132 + (tc << 2)];
    float ps = v.x * as4.x + v.y * as4.y + v.z * as4.z + v.w * as4.w;
    float pd = v.x * ad4.x + v.y * ad4.y + v.z * ad4.z + v.w * ad4.w;
    ps += __shfl_xor(ps, 1); ps += __shfl_xor(ps, 2); ps += __shfl_xor(ps, 4);
    pd += __shfl_xor(pd, 1); pd += __shfl_xor(pd, 2); pd += __shfl_xor(pd, 4);
    if (grow < NNODES) {
      u16 q[4] = {f2b(v.x), f2b(v.y), f2b(v.z), f2b(v.w)};
      *(ushort4*)&hb[(size_t)grow * HC + (tc << 2)] = *(ushort4*)q;
      if ((tc & 7) == 0) {
        nrec[(size_t)grow * NR + head] = ps;       // s_src
        nrec[(size_t)grow * NR + 4 + head] = pd;   // s_dst
      }
    }
  }
}

// ---- K2: chunked LDS histogram (u16-packed), per-edge local slot ----
__global__ __launch_bounds__(256) void k_chist(const int* __restrict__ rowi,
                                               u32* __restrict__ chunk_hist,
                                               u16* __restrict__ lslot) {
  __shared__ u32 lh[WORDS];  // 100 KB
  const int c = blockIdx.x;
  const int tid = threadIdx.x;
  for (int i = tid; i < WORDS; i += 256) lh[i] = 0;
  __syncthreads();
  const int base = c * CE;
  for (int i = tid; i < CE; i += 256) {
    int e = base + i;
    int r = rowi[e];
    u32 sh = (u32)(r & 1) << 4;
    u32 old = atomicAdd(&lh[r >> 1], 1u << sh);
    lslot[e] = (u16)((old >> sh) & 0xFFFFu);
  }
  __syncthreads();
  u32* dst = chunk_hist + (size_t)c * WORDS;
  for (int i = tid; i < WORDS; i += 256) dst[i] = lh[i];
}

// ---- K3: in-place column scan of chunk_hist over chunks; per-row totals ----
__global__ __launch_bounds__(256) void k_cscan(u32* __restrict__ chunk_hist,
                                               int* __restrict__ counts) {
  __shared__ u32 tile[NCHUNK][64];  // 32 KB
  const int w0 = blockIdx.x * 64;
  const int tid = threadIdx.x;
  for (int i = tid; i < NCHUNK * 64; i += 256) {
    int c = i >> 6, wl = i & 63;
    int w = w0 + wl;
    tile[c][wl] = (w < WORDS) ? chunk_hist[(size_t)c * WORDS + w] : 0u;
  }
  __syncthreads();
  if (tid < 64) {
    u32 slo = 0, shi = 0;
    for (int c = 0; c < NCHUNK; ++c) {
      u32 v = tile[c][tid];
      tile[c][tid] = slo | (shi << 16);
      slo += v & 0xFFFFu;
      shi += v >> 16;
    }
    int w = w0 + tid;
    if (w < WORDS) {
      int r = w << 1;
      if (r < NNODES) counts[r] = (int)slo;
      if (r + 1 < NNODES) counts[r + 1] = (int)shi;
    }
  }
  __syncthreads();
  for (int i = tid; i < NCHUNK * 64; i += 256) {
    int c = i >> 6, wl = i & 63;
    int w = w0 + wl;
    if (w < WORDS) chunk_hist[(size_t)c * WORDS + w] = tile[c][wl];
  }
}

// ---- K4a/b/c: full-GPU 3-phase exclusive scan of counts -> row_ptr ----
__global__ __launch_bounds__(256) void k_scan1(const int* __restrict__ counts,
                                               int* __restrict__ bsum) {
  int i = blockIdx.x * 256 + threadIdx.x;
  int v = (i < NNODES) ? counts[i] : 0;
#pragma unroll
  for (int m = 1; m < 64; m <<= 1) v += __shfl_xor(v, m);
  __shared__ int ws[4];
  if ((threadIdx.x & 63) == 0) ws[threadIdx.x >> 6] = v;
  __syncthreads();
  if (threadIdx.x == 0) bsum[blockIdx.x] = ws[0] + ws[1] + ws[2] + ws[3];
}

__global__ __launch_bounds__(256) void k_scan2(const int* __restrict__ bsum,
                                               int* __restrict__ boff) {
  __shared__ int s[256];
  int t = threadIdx.x;
  int v = (t < NSB) ? bsum[t] : 0;
  s[t] = v;
  __syncthreads();
  for (int off = 1; off < 256; off <<= 1) {
    int u = (t >= off) ? s[t - off] : 0;
    __syncthreads();
    s[t] += u;
    __syncthreads();
  }
  boff[t] = s[t] - v;
}

__global__ __launch_bounds__(256) void k_scan3(const int* __restrict__ counts,
                                               const int* __restrict__ boff,
                                               int* __restrict__ row_ptr) {
  __shared__ int s[256];
  int t = threadIdx.x;
  int i = blockIdx.x * 256 + t;
  int v = (i < NNODES) ? counts[i] : 0;
  s[t] = v;
  __syncthreads();
  for (int off = 1; off < 256; off <<= 1) {
    int u = (t >= off) ? s[t - off] : 0;
    __syncthreads();
    s[t] += u;
    __syncthreads();
  }
  if (i < NNODES) row_ptr[i] = boff[blockIdx.x] + s[t] - v;
  if (i == 0) row_ptr[NNODES] = NEDGES;
}

// ---- K5: atomic-free scatter of col (u16) into CSR — ONE 2B random store/edge ----
__global__ void k_scatter(const int* __restrict__ rowi, const int* __restrict__ coli,
                          const int* __restrict__ row_ptr,
                          const u32* __restrict__ chunk_hist,
                          const u16* __restrict__ lslot,
                          u16* __restrict__ col_csr) {
  int e = blockIdx.x * 256 + threadIdx.x;
  if (e >= NEDGES) return;
  int r = rowi[e];
  int c = e / CE;
  u32 word = chunk_hist[(size_t)c * WORDS + (r >> 1)];
  int off = (int)((word >> ((u32)(r & 1) << 4)) & 0xFFFFu);
  int pos = row_ptr[r] + off + (int)lslot[e];
  col_csr[pos] = (u16)coli[e];
}

// ---- K6: per-row wave softmax: writes mx/rden into nrec + bf16 an in CSR order ----
__global__ __launch_bounds__(256) void k_softmax(const u16* __restrict__ col_csr,
                                                 const int* __restrict__ row_ptr,
                                                 float* __restrict__ nrec,
                                                 u16* __restrict__ an16) {
  const int wid = threadIdx.x >> 6;
  const int lane = threadIdx.x & 63;
  const int r = blockIdx.x * 4 + wid;
  if (r >= NNODES) return;
  const int p0 = row_ptr[r], p1 = row_ptr[r + 1];
  const int deg = p1 - p0;
  if (deg == 0) return;
  const float4 ss = *(const float4*)&nrec[(size_t)r * NR];
  const float NEG = -3.0e38f;

  if (deg <= 64) {
    float4 al = make_float4(NEG, NEG, NEG, NEG);
    if (lane < deg) {
      int c = col_csr[p0 + lane];
      float4 sd = *(const float4*)&nrec[(size_t)c * NR + 4];
      al.x = lrelu(ss.x + sd.x);
      al.y = lrelu(ss.y + sd.y);
      al.z = lrelu(ss.z + sd.z);
      al.w = lrelu(ss.w + sd.w);
    }
    float4 mx = al;
#pragma unroll
    for (int m = 1; m < 64; m <<= 1) {
      mx.x = fmaxf(mx.x, __shfl_xor(mx.x, m));
      mx.y = fmaxf(mx.y, __shfl_xor(mx.y, m));
      mx.z = fmaxf(mx.z, __shfl_xor(mx.z, m));
      mx.w = fmaxf(mx.w, __shfl_xor(mx.w, m));
    }
    float4 ex = make_float4(0.f, 0.f, 0.f, 0.f);
    if (lane < deg) {
      ex.x = __expf(al.x - mx.x);
      ex.y = __expf(al.y - mx.y);
      ex.z = __expf(al.z - mx.z);
      ex.w = __expf(al.w - mx.w);
    }
    float4 sm = ex;
#pragma unroll
    for (int m = 1; m < 64; m <<= 1) {
      sm.x += __shfl_xor(sm.x, m);
      sm.y += __shfl_xor(sm.y, m);
      sm.z += __shfl_xor(sm.z, m);
      sm.w += __shfl_xor(sm.w, m);
    }
    float4 rd = make_float4(1.f / sm.x, 1.f / sm.y, 1.f / sm.z, 1.f / sm.w);
    if (lane == 0) {
      *(float4*)&nrec[(size_t)r * NR + 8] = mx;
      *(float4*)&nrec[(size_t)r * NR + 12] = rd;
    }
    if (lane < deg) {
      u16 q[4] = {f2b(ex.x * rd.x), f2b(ex.y * rd.y), f2b(ex.z * rd.z), f2b(ex.w * rd.w)};
      *(ushort4*)&an16[(size_t)(p0 + lane) * 4] = *(ushort4*)q;
    }
  } else {
    float4 mx = make_float4(NEG, NEG, NEG, NEG);
    for (int p = p0 + lane; p < p1; p += 64) {
      int c = col_csr[p];
      float4 sd = *(const float4*)&nrec[(size_t)c * NR + 4];
      mx.x = fmaxf(mx.x, lrelu(ss.x + sd.x));
      mx.y = fmaxf(mx.y, lrelu(ss.y + sd.y));
      mx.z = fmaxf(mx.z, lrelu(ss.z + sd.z));
      mx.w = fmaxf(mx.w, lrelu(ss.w + sd.w));
    }
#pragma unroll
    for (int m = 1; m < 64; m <<= 1) {
      mx.x = fmaxf(mx.x, __shfl_xor(mx.x, m));
      mx.y = fmaxf(mx.y, __shfl_xor(mx.y, m));
      mx.z = fmaxf(mx.z, __shfl_xor(mx.z, m));
      mx.w = fmaxf(mx.w, __shfl_xor(mx.w, m));
    }
    float4 sm = make_float4(0.f, 0.f, 0.f, 0.f);
    for (int p = p0 + lane; p < p1; p += 64) {
      int c = col_csr[p];
      float4 sd = *(const float4*)&nrec[(size_t)c * NR + 4];
      sm.x += __expf(lrelu(ss.x + sd.x) - mx.x);
      sm.y += __expf(lrelu(ss.y + sd.y) - mx.y);
      sm.z += __expf(lrelu(ss.z + sd.z) - mx.z);
      sm.w += __expf(lrelu(ss.w + sd.w) - mx.w);
    }
#pragma unroll
    for (int m = 1; m < 64; m <<= 1) {
      sm.x += __shfl_xor(sm.x, m);
      sm.y += __shfl_xor(sm.y, m);
      sm.z += __shfl_xor(sm.z, m);
      sm.w += __shfl_xor(sm.w, m);
    }
    float4 rd = make_float4(1.f / sm.x, 1.f / sm.y, 1.f / sm.z, 1.f / sm.w);
    if (lane == 0) {
      *(float4*)&nrec[(size_t)r * NR + 8] = mx;
      *(float4*)&nrec[(size_t)r * NR + 12] = rd;
    }
    for (int p = p0 + lane; p < p1; p += 64) {
      int c = col_csr[p];
      float4 sd = *(const float4*)&nrec[(size_t)c * NR + 4];
      float4 ex;
      ex.x = __expf(lrelu(ss.x + sd.x) - mx.x) * rd.x;
      ex.y = __expf(lrelu(ss.y + sd.y) - mx.y) * rd.y;
      ex.z = __expf(lrelu(ss.z + sd.z) - mx.z) * rd.z;
      ex.w = __expf(lrelu(ss.w + sd.w) - mx.w) * rd.w;
      u16 q[4] = {f2b(ex.x), f2b(ex.y), f2b(ex.z), f2b(ex.w)};
      *(ushort4*)&an16[(size_t)p * 4] = *(ushort4*)q;
    }
  }
}

// ---- K7: alpha_norm in original edge order (coalesced float4 writes);
//      r-side tables (ss,mx,rd) live in one 64B nrec line ----
__global__ void k_alphaf(const int* __restrict__ rowi, const int* __restrict__ coli,
                         const float* __restrict__ nrec,
                         float* __restrict__ alpha_out) {
  int e = blockIdx.x * 256 + threadIdx.x;
  if (e >= NEDGES) return;
  int r = rowi[e], c = coli[e];
  const float* nr = &nrec[(size_t)r * NR];
  float4 ss = *(const float4*)(nr);
  float4 m4 = *(const float4*)(nr + 8);
  float4 rd = *(const float4*)(nr + 12);
  float4 sd = *(const float4*)&nrec[(size_t)c * NR + 4];
  float4 an;
  an.x = __expf(lrelu(ss.x + sd.x) - m4.x) * rd.x;
  an.y = __expf(lrelu(ss.y + sd.y) - m4.y) * rd.y;
  an.z = __expf(lrelu(ss.z + sd.z) - m4.z) * rd.z;
  an.w = __expf(lrelu(ss.w + sd.w) - m4.w) * rd.w;
  *(float4*)&alpha_out[(size_t)e * 4] = an;
}

// ---- K8: per-row wave aggregation, 8-deep gather pipeline (R5 structure,
//      best measured: 57.8us, occ 66%). 2 channels/lane, serial remainder. ----
__global__ __launch_bounds__(256) void k_aggr(const u16* __restrict__ col_csr,
                                              const int* __restrict__ row_ptr,
                                              const u16* __restrict__ an16,
                                              const u16* __restrict__ hb,
                                              float* __restrict__ out_mean) {
  const int wid = threadIdx.x >> 6;
  const int lane = threadIdx.x & 63;
  const int r = blockIdx.x * 4 + wid;
  if (r >= NNODES) return;
  const int p0 = row_ptr[r], p1 = row_ptr[r + 1];
  const int hd = lane >> 4;
  const int ch = lane << 1;
  float acc0 = 0.f, acc1 = 0.f;

  int p = p0;
  for (; p + 8 <= p1; p += 8) {
    int cs[8];
    float ws[8];
    u32 hv[8];
#pragma unroll
    for (int i = 0; i < 8; ++i) cs[i] = col_csr[p + i];
#pragma unroll
    for (int i = 0; i < 8; ++i) ws[i] = b2f(an16[(size_t)(p + i) * 4 + hd]);
#pragma unroll
    for (int i = 0; i < 8; ++i) hv[i] = *(const u32*)&hb[(size_t)cs[i] * HC + ch];
#pragma unroll
    for (int i = 0; i < 8; ++i) {
      acc0 += ws[i] * b2f((u16)(hv[i] & 0xFFFFu));
      acc1 += ws[i] * b2f((u16)(hv[i] >> 16));
    }
  }
  for (; p < p1; ++p) {
    int c = col_csr[p];
    float w = b2f(an16[(size_t)p * 4 + hd]);
    u32 hv = *(const u32*)&hb[(size_t)c * HC + ch];
    acc0 += w * b2f((u16)(hv & 0xFFFFu));
    acc1 += w * b2f((u16)(hv >> 16));
  }
  acc0 += __shfl_xor(acc0, 16);
  acc0 += __shfl_xor(acc0, 32);
  acc1 += __shfl_xor(acc1, 16);
  acc1 += __shfl_xor(acc1, 32);
  if (lane < 16) {
    float2 o = make_float2(acc0 * 0.25f, acc1 * 0.25f);
    *(float2*)&out_mean[(size_t)r * 32 + (lane << 1)] = o;
  }
}

extern "C" void kernel_launch(void* const* d_in, const int* in_sizes, int n_in,
                              void* d_out, int out_size, void* d_ws, size_t ws_size,
                              hipStream_t stream) {
  const float* x = (const float*)d_in[0];
  const int* ei = (const int*)d_in[1];
  const float* W = (const float*)d_in[2];
  const float* attn = (const float*)d_in[3];
  const int* rowi = ei;
  const int* coli = ei + NEDGES;

  float* out_mean = (float*)d_out;
  float* alpha_out = (float*)d_out + (size_t)NNODES * 32;

  char* w = (char*)d_ws;
  u16* hb = (u16*)w;          w += (size_t)NNODES * HC * 2;       // 12.8 MB
  u16* an16 = (u16*)w;        w += (size_t)NEDGES * 4 * 2;        // 12.8 MB
  float* nrec = (float*)w;    w += (size_t)NNODES * NR * 4;       // 3.2 MB (64B/node)
  int* counts = (int*)w;      w += (size_t)NNODES * 4;
  int* bsum = (int*)w;        w += (size_t)256 * 4;
  int* boff = (int*)w;        w += (size_t)256 * 4;
  int* row_ptr = (int*)w;     w += (size_t)50016 * 4;
  u16* lslot = (u16*)w;       w += (size_t)NEDGES * 2;            // 3.2 MB
  u16* col_csr = (u16*)w;     w += (size_t)NEDGES * 2;            // 3.2 MB
  u32* chunk_hist = (u32*)w;  w += (size_t)NCHUNK * WORDS * 4;    // 12.8 MB
  u16* wt = (u16*)w;          w += (size_t)IN_CH * HC * 2;        // 64 KB

  k_wprep<<<(IN_CH * HC + 255) / 256, 256, 0, stream>>>(W, wt);
  k_gemm<<<(NNODES + 63) / 64, 256, 0, stream>>>(x, wt, attn, hb, nrec);
  k_chist<<<NCHUNK, 256, 0, stream>>>(rowi, chunk_hist, lslot);
  k_cscan<<<(WORDS + 63) / 64, 256, 0, stream>>>(chunk_hist, counts);
  k_scan1<<<NSB, 256, 0, stream>>>(counts, bsum);
  k_scan2<<<1, 256, 0, stream>>>(bsum, boff);
  k_scan3<<<NSB, 256, 0, stream>>>(counts, boff, row_ptr);
  k_scatter<<<(NEDGES + 255) / 256, 256, 0, stream>>>(rowi, coli, row_ptr, chunk_hist, lslot, col_csr);
  k_softmax<<<(NNODES + 3) / 4, 256, 0, stream>>>(col_csr, row_ptr, nrec, an16);
  k_alphaf<<<(NEDGES + 255) / 256, 256, 0, stream>>>(rowi, coli, nrec, alpha_out);
  k_aggr<<<(NNODES + 3) / 4, 256, 0, stream>>>(col_csr, row_ptr, an16, hb, out_mean);
}

// Round 12
// 201.762 us; speedup vs baseline: 1.3462x; 1.1177x over previous
//
#include <hip/hip_runtime.h>

#define NNODES 50000
#define NEDGES 1600000
#define IN_CH 256
#define HEADS 4
#define OUT_CH 32
#define HC 128                       // HEADS*OUT_CH
#define NSB ((NNODES + 255) / 256)   // 196 scan blocks
#define NCHUNK 128
#define CE 12500                     // edges per chunk; 128*12500 == NEDGES
#define WORDS 25000                  // u32 words per chunk hist (2 u16 bins/word)

#define GEMM_BLOCKS ((NNODES + 63) / 64)        // 782
#define SCAT_BLOCKS ((NEDGES + 1023) / 1024)    // 1563 (4 edges/thread)
#define AGGR_BLOCKS ((NNODES + 3) / 4)          // 12500
#define ALPHA_BLOCKS ((NEDGES + 255) / 256)     // 6250

typedef unsigned int u32;
typedef unsigned short u16;
typedef short bf16x8 __attribute__((ext_vector_type(8)));   // 8 bf16 in 4 VGPRs
typedef u16 u16x8 __attribute__((ext_vector_type(8)));
typedef float f32x4 __attribute__((ext_vector_type(4)));

__device__ __forceinline__ float b2f(u16 s) { return __uint_as_float(((u32)s) << 16); }
__device__ __forceinline__ u16 f2b(float f) {
  u32 u = __float_as_uint(f);
  u32 r = (u + 0x7FFFu + ((u >> 16) & 1u)) >> 16;
  return (u16)r;
}
__device__ __forceinline__ float lrelu(float v) { return v >= 0.f ? v : 0.2f * v; }

// node record layout (16 floats = 64B): [0:4)=s_src, [4:8)=s_dst, [8:12)=mx, [12:16)=rden
#define NR 16

// ---- K0: W (256x128 f32) -> bf16, transposed+tiled: wt[((kt*128+n)*32+kk)] ----
__global__ __launch_bounds__(256) void k_wprep(const float* __restrict__ W,
                                               u16* __restrict__ wt) {
  int i = blockIdx.x * 256 + threadIdx.x;   // 0..32767
  if (i >= IN_CH * HC) return;
  int kk = i & 31;
  int n = (i >> 5) & 127;
  int kt = i >> 12;
  wt[i] = f2b(W[(size_t)(kt * 32 + kk) * HC + n]);
}

// ---- K1 (merged): blocks [0,GEMM_BLOCKS) = MFMA gemm+scores;
//      blocks [GEMM_BLOCKS, +SCAT_BLOCKS) = CSR scatter (independent work) ----
__global__ __launch_bounds__(256) void k_gemscat(const float* __restrict__ x,
                                                 const u16* __restrict__ wt,
                                                 const float* __restrict__ attn,
                                                 u16* __restrict__ hb,
                                                 float* __restrict__ nrec,
                                                 const int* __restrict__ rowi,
                                                 const int* __restrict__ coli,
                                                 const int* __restrict__ row_ptr,
                                                 const u32* __restrict__ chunk_hist,
                                                 const u16* __restrict__ lslot,
                                                 u16* __restrict__ col_csr) {
  __shared__ union {
    struct {
      u16 xh[64 * 32];    // 4 KB, XOR-swizzled
      u16 xl[64 * 32];    // 4 KB
      u16 wh[128 * 32];   // 8 KB
    } st;
    float cbuf[64 * 132]; // 33.8 KB (row stride 132 f32)
  } L;
  __shared__ float sA[256];
  const int tid = threadIdx.x;

  if (blockIdx.x >= GEMM_BLOCKS) {
    // ---- scatter role: 4 edges per thread ----
    const int base = (blockIdx.x - GEMM_BLOCKS) * 1024 + tid;
#pragma unroll
    for (int k = 0; k < 4; ++k) {
      int e = base + k * 256;
      if (e < NEDGES) {
        int r = rowi[e];
        int c = e / CE;
        u32 word = chunk_hist[(size_t)c * WORDS + (r >> 1)];
        int off = (int)((word >> ((u32)(r & 1) << 4)) & 0xFFFFu);
        int pos = row_ptr[r] + off + (int)lslot[e];
        col_csr[pos] = (u16)coli[e];
      }
    }
    return;
  }

  // ---- gemm role (identical to R11 k_gemm) ----
  const int wave = tid >> 6;
  const int lane = tid & 63;
  const int row0 = blockIdx.x * 64;
  sA[tid] = attn[tid];

  f32x4 acc[4][2] = {};
  const int frow = lane & 15;
  const int koff = (lane >> 4) << 4;

  const int sr = tid >> 2;
  const int skc = (tid & 3) << 3;
  const int sgrow = row0 + sr;
  const int sxb = (sr << 6) + (skc << 1);
  const int sxs = sxb ^ ((sr & 7) << 4);

  for (int kt = 0; kt < 8; ++kt) {
    {
      float4 v0 = make_float4(0.f, 0.f, 0.f, 0.f), v1 = v0;
      if (sgrow < NNODES) {
        const float* px = &x[(size_t)sgrow * IN_CH + kt * 32 + skc];
        v0 = *(const float4*)px;
        v1 = *(const float4*)(px + 4);
      }
      float vv[8] = {v0.x, v0.y, v0.z, v0.w, v1.x, v1.y, v1.z, v1.w};
      u16x8 hi, lo;
#pragma unroll
      for (int i = 0; i < 8; ++i) {
        u16 h = f2b(vv[i]);
        hi[i] = h;
        lo[i] = f2b(vv[i] - b2f(h));
      }
      *(u16x8*)((char*)L.st.xh + sxs) = hi;
      *(u16x8*)((char*)L.st.xl + sxs) = lo;
    }
#pragma unroll
    for (int li = 0; li < 2; ++li) {
      int i = tid + (li << 8);
      int col = i >> 2;
      int kb = (i & 3) << 4;
      u16x8 v = *(const u16x8*)((const char*)wt + (((size_t)(kt * 128 + col)) << 6) + kb);
      int sb = ((col << 6) + kb) ^ ((col & 7) << 4);
      *(u16x8*)((char*)L.st.wh + sb) = v;
    }
    __syncthreads();
    bf16x8 ah[4], al[4], bw[2];
#pragma unroll
    for (int mi = 0; mi < 4; ++mi) {
      int r = mi * 16 + frow;
      int sb = ((r << 6) + koff) ^ ((r & 7) << 4);
      ah[mi] = *(bf16x8*)((char*)L.st.xh + sb);
      al[mi] = *(bf16x8*)((char*)L.st.xl + sb);
    }
#pragma unroll
    for (int ni = 0; ni < 2; ++ni) {
      int c = (wave << 5) + ni * 16 + frow;
      int sb = ((c << 6) + koff) ^ ((c & 7) << 4);
      bw[ni] = *(bf16x8*)((char*)L.st.wh + sb);
    }
#pragma unroll
    for (int mi = 0; mi < 4; ++mi)
#pragma unroll
      for (int ni = 0; ni < 2; ++ni) {
        acc[mi][ni] = __builtin_amdgcn_mfma_f32_16x16x32_bf16(ah[mi], bw[ni], acc[mi][ni], 0, 0, 0);
        acc[mi][ni] = __builtin_amdgcn_mfma_f32_16x16x32_bf16(al[mi], bw[ni], acc[mi][ni], 0, 0, 0);
      }
    __syncthreads();
  }

#pragma unroll
  for (int mi = 0; mi < 4; ++mi)
#pragma unroll
    for (int ni = 0; ni < 2; ++ni) {
#pragma unroll
      for (int reg = 0; reg < 4; ++reg) {
        int row = mi * 16 + ((lane >> 4) << 2) + reg;
        int col = (wave << 5) + (ni << 4) + frow;
        L.cbuf[row * 132 + col] = acc[mi][ni][reg];
      }
    }
  __syncthreads();

  const int tc = tid & 31;
  const int tr = tid >> 5;
  const int head = tc >> 3;
  const int cb = (tc & 7) << 2;
  const float4 as4 = *(const float4*)&sA[head * 64 + cb];
  const float4 ad4 = *(const float4*)&sA[head * 64 + 32 + cb];
#pragma unroll
  for (int i = 0; i < 8; ++i) {
    int row = (tr << 3) + i;
    int grow = row0 + row;
    float4 v = *(const float4*)&L.cbuf[row * 132 + (tc << 2)];
    float ps = v.x * as4.x + v.y * as4.y + v.z * as4.z + v.w * as4.w;
    float pd = v.x * ad4.x + v.y * ad4.y + v.z * ad4.z + v.w * ad4.w;
    ps += __shfl_xor(ps, 1); ps += __shfl_xor(ps, 2); ps += __shfl_xor(ps, 4);
    pd += __shfl_xor(pd, 1); pd += __shfl_xor(pd, 2); pd += __shfl_xor(pd, 4);
    if (grow < NNODES) {
      u16 q[4] = {f2b(v.x), f2b(v.y), f2b(v.z), f2b(v.w)};
      *(ushort4*)&hb[(size_t)grow * HC + (tc << 2)] = *(ushort4*)q;
      if ((tc & 7) == 0) {
        nrec[(size_t)grow * NR + head] = ps;       // s_src
        nrec[(size_t)grow * NR + 4 + head] = pd;   // s_dst
      }
    }
  }
}

// ---- K2: chunked LDS histogram (u16-packed), per-edge local slot ----
__global__ __launch_bounds__(256) void k_chist(const int* __restrict__ rowi,
                                               u32* __restrict__ chunk_hist,
                                               u16* __restrict__ lslot) {
  __shared__ u32 lh[WORDS];  // 100 KB
  const int c = blockIdx.x;
  const int tid = threadIdx.x;
  for (int i = tid; i < WORDS; i += 256) lh[i] = 0;
  __syncthreads();
  const int base = c * CE;
  for (int i = tid; i < CE; i += 256) {
    int e = base + i;
    int r = rowi[e];
    u32 sh = (u32)(r & 1) << 4;
    u32 old = atomicAdd(&lh[r >> 1], 1u << sh);
    lslot[e] = (u16)((old >> sh) & 0xFFFFu);
  }
  __syncthreads();
  u32* dst = chunk_hist + (size_t)c * WORDS;
  for (int i = tid; i < WORDS; i += 256) dst[i] = lh[i];
}

// ---- K3: in-place column scan of chunk_hist over chunks; per-row totals ----
__global__ __launch_bounds__(256) void k_cscan(u32* __restrict__ chunk_hist,
                                               int* __restrict__ counts) {
  __shared__ u32 tile[NCHUNK][64];  // 32 KB
  const int w0 = blockIdx.x * 64;
  const int tid = threadIdx.x;
  for (int i = tid; i < NCHUNK * 64; i += 256) {
    int c = i >> 6, wl = i & 63;
    int w = w0 + wl;
    tile[c][wl] = (w < WORDS) ? chunk_hist[(size_t)c * WORDS + w] : 0u;
  }
  __syncthreads();
  if (tid < 64) {
    u32 slo = 0, shi = 0;
    for (int c = 0; c < NCHUNK; ++c) {
      u32 v = tile[c][tid];
      tile[c][tid] = slo | (shi << 16);
      slo += v & 0xFFFFu;
      shi += v >> 16;
    }
    int w = w0 + tid;
    if (w < WORDS) {
      int r = w << 1;
      if (r < NNODES) counts[r] = (int)slo;
      if (r + 1 < NNODES) counts[r + 1] = (int)shi;
    }
  }
  __syncthreads();
  for (int i = tid; i < NCHUNK * 64; i += 256) {
    int c = i >> 6, wl = i & 63;
    int w = w0 + wl;
    if (w < WORDS) chunk_hist[(size_t)c * WORDS + w] = tile[c][wl];
  }
}

// ---- K4a/b/c: full-GPU 3-phase exclusive scan of counts -> row_ptr ----
__global__ __launch_bounds__(256) void k_scan1(const int* __restrict__ counts,
                                               int* __restrict__ bsum) {
  int i = blockIdx.x * 256 + threadIdx.x;
  int v = (i < NNODES) ? counts[i] : 0;
#pragma unroll
  for (int m = 1; m < 64; m <<= 1) v += __shfl_xor(v, m);
  __shared__ int ws[4];
  if ((threadIdx.x & 63) == 0) ws[threadIdx.x >> 6] = v;
  __syncthreads();
  if (threadIdx.x == 0) bsum[blockIdx.x] = ws[0] + ws[1] + ws[2] + ws[3];
}

__global__ __launch_bounds__(256) void k_scan2(const int* __restrict__ bsum,
                                               int* __restrict__ boff) {
  __shared__ int s[256];
  int t = threadIdx.x;
  int v = (t < NSB) ? bsum[t] : 0;
  s[t] = v;
  __syncthreads();
  for (int off = 1; off < 256; off <<= 1) {
    int u = (t >= off) ? s[t - off] : 0;
    __syncthreads();
    s[t] += u;
    __syncthreads();
  }
  boff[t] = s[t] - v;
}

__global__ __launch_bounds__(256) void k_scan3(const int* __restrict__ counts,
                                               const int* __restrict__ boff,
                                               int* __restrict__ row_ptr) {
  __shared__ int s[256];
  int t = threadIdx.x;
  int i = blockIdx.x * 256 + t;
  int v = (i < NNODES) ? counts[i] : 0;
  s[t] = v;
  __syncthreads();
  for (int off = 1; off < 256; off <<= 1) {
    int u = (t >= off) ? s[t - off] : 0;
    __syncthreads();
    s[t] += u;
    __syncthreads();
  }
  if (i < NNODES) row_ptr[i] = boff[blockIdx.x] + s[t] - v;
  if (i == 0) row_ptr[NNODES] = NEDGES;
}

// ---- K6: per-row wave softmax: writes mx/rden into nrec + bf16 an in CSR order ----
__global__ __launch_bounds__(256) void k_softmax(const u16* __restrict__ col_csr,
                                                 const int* __restrict__ row_ptr,
                                                 float* __restrict__ nrec,
                                                 u16* __restrict__ an16) {
  const int wid = threadIdx.x >> 6;
  const int lane = threadIdx.x & 63;
  const int r = blockIdx.x * 4 + wid;
  if (r >= NNODES) return;
  const int p0 = row_ptr[r], p1 = row_ptr[r + 1];
  const int deg = p1 - p0;
  if (deg == 0) return;
  const float4 ss = *(const float4*)&nrec[(size_t)r * NR];
  const float NEG = -3.0e38f;

  if (deg <= 64) {
    float4 al = make_float4(NEG, NEG, NEG, NEG);
    if (lane < deg) {
      int c = col_csr[p0 + lane];
      float4 sd = *(const float4*)&nrec[(size_t)c * NR + 4];
      al.x = lrelu(ss.x + sd.x);
      al.y = lrelu(ss.y + sd.y);
      al.z = lrelu(ss.z + sd.z);
      al.w = lrelu(ss.w + sd.w);
    }
    float4 mx = al;
#pragma unroll
    for (int m = 1; m < 64; m <<= 1) {
      mx.x = fmaxf(mx.x, __shfl_xor(mx.x, m));
      mx.y = fmaxf(mx.y, __shfl_xor(mx.y, m));
      mx.z = fmaxf(mx.z, __shfl_xor(mx.z, m));
      mx.w = fmaxf(mx.w, __shfl_xor(mx.w, m));
    }
    float4 ex = make_float4(0.f, 0.f, 0.f, 0.f);
    if (lane < deg) {
      ex.x = __expf(al.x - mx.x);
      ex.y = __expf(al.y - mx.y);
      ex.z = __expf(al.z - mx.z);
      ex.w = __expf(al.w - mx.w);
    }
    float4 sm = ex;
#pragma unroll
    for (int m = 1; m < 64; m <<= 1) {
      sm.x += __shfl_xor(sm.x, m);
      sm.y += __shfl_xor(sm.y, m);
      sm.z += __shfl_xor(sm.z, m);
      sm.w += __shfl_xor(sm.w, m);
    }
    float4 rd = make_float4(1.f / sm.x, 1.f / sm.y, 1.f / sm.z, 1.f / sm.w);
    if (lane == 0) {
      *(float4*)&nrec[(size_t)r * NR + 8] = mx;
      *(float4*)&nrec[(size_t)r * NR + 12] = rd;
    }
    if (lane < deg) {
      u16 q[4] = {f2b(ex.x * rd.x), f2b(ex.y * rd.y), f2b(ex.z * rd.z), f2b(ex.w * rd.w)};
      *(ushort4*)&an16[(size_t)(p0 + lane) * 4] = *(ushort4*)q;
    }
  } else {
    float4 mx = make_float4(NEG, NEG, NEG, NEG);
    for (int p = p0 + lane; p < p1; p += 64) {
      int c = col_csr[p];
      float4 sd = *(const float4*)&nrec[(size_t)c * NR + 4];
      mx.x = fmaxf(mx.x, lrelu(ss.x + sd.x));
      mx.y = fmaxf(mx.y, lrelu(ss.y + sd.y));
      mx.z = fmaxf(mx.z, lrelu(ss.z + sd.z));
      mx.w = fmaxf(mx.w, lrelu(ss.w + sd.w));
    }
#pragma unroll
    for (int m = 1; m < 64; m <<= 1) {
      mx.x = fmaxf(mx.x, __shfl_xor(mx.x, m));
      mx.y = fmaxf(mx.y, __shfl_xor(mx.y, m));
      mx.z = fmaxf(mx.z, __shfl_xor(mx.z, m));
      mx.w = fmaxf(mx.w, __shfl_xor(mx.w, m));
    }
    float4 sm = make_float4(0.f, 0.f, 0.f, 0.f);
    for (int p = p0 + lane; p < p1; p += 64) {
      int c = col_csr[p];
      float4 sd = *(const float4*)&nrec[(size_t)c * NR + 4];
      sm.x += __expf(lrelu(ss.x + sd.x) - mx.x);
      sm.y += __expf(lrelu(ss.y + sd.y) - mx.y);
      sm.z += __expf(lrelu(ss.z + sd.z) - mx.z);
      sm.w += __expf(lrelu(ss.w + sd.w) - mx.w);
    }
#pragma unroll
    for (int m = 1; m < 64; m <<= 1) {
      sm.x += __shfl_xor(sm.x, m);
      sm.y += __shfl_xor(sm.y, m);
      sm.z += __shfl_xor(sm.z, m);
      sm.w += __shfl_xor(sm.w, m);
    }
    float4 rd = make_float4(1.f / sm.x, 1.f / sm.y, 1.f / sm.z, 1.f / sm.w);
    if (lane == 0) {
      *(float4*)&nrec[(size_t)r * NR + 8] = mx;
      *(float4*)&nrec[(size_t)r * NR + 12] = rd;
    }
    for (int p = p0 + lane; p < p1; p += 64) {
      int c = col_csr[p];
      float4 sd = *(const float4*)&nrec[(size_t)c * NR + 4];
      float4 ex;
      ex.x = __expf(lrelu(ss.x + sd.x) - mx.x) * rd.x;
      ex.y = __expf(lrelu(ss.y + sd.y) - mx.y) * rd.y;
      ex.z = __expf(lrelu(ss.z + sd.z) - mx.z) * rd.z;
      ex.w = __expf(lrelu(ss.w + sd.w) - mx.w) * rd.w;
      u16 q[4] = {f2b(ex.x), f2b(ex.y), f2b(ex.z), f2b(ex.w)};
      *(ushort4*)&an16[(size_t)p * 4] = *(ushort4*)q;
    }
  }
}

// ---- K7 (merged): blocks [0,AGGR_BLOCKS) = aggregation (long pole);
//      blocks [AGGR_BLOCKS, +ALPHA_BLOCKS) = alpha_norm edge-order write ----
__global__ __launch_bounds__(256) void k_alphaggr(const u16* __restrict__ col_csr,
                                                  const int* __restrict__ row_ptr,
                                                  const u16* __restrict__ an16,
                                                  const u16* __restrict__ hb,
                                                  float* __restrict__ out_mean,
                                                  const int* __restrict__ rowi,
                                                  const int* __restrict__ coli,
                                                  const float* __restrict__ nrec,
                                                  float* __restrict__ alpha_out) {
  if (blockIdx.x >= AGGR_BLOCKS) {
    // ---- alphaf role ----
    int e = (blockIdx.x - AGGR_BLOCKS) * 256 + threadIdx.x;
    if (e >= NEDGES) return;
    int r = rowi[e], c = coli[e];
    const float* nr = &nrec[(size_t)r * NR];
    float4 ss = *(const float4*)(nr);
    float4 m4 = *(const float4*)(nr + 8);
    float4 rd = *(const float4*)(nr + 12);
    float4 sd = *(const float4*)&nrec[(size_t)c * NR + 4];
    float4 an;
    an.x = __expf(lrelu(ss.x + sd.x) - m4.x) * rd.x;
    an.y = __expf(lrelu(ss.y + sd.y) - m4.y) * rd.y;
    an.z = __expf(lrelu(ss.z + sd.z) - m4.z) * rd.z;
    an.w = __expf(lrelu(ss.w + sd.w) - m4.w) * rd.w;
    *(float4*)&alpha_out[(size_t)e * 4] = an;
    return;
  }
  // ---- aggr role (identical to R11 k_aggr) ----
  const int wid = threadIdx.x >> 6;
  const int lane = threadIdx.x & 63;
  const int r = blockIdx.x * 4 + wid;
  if (r >= NNODES) return;
  const int p0 = row_ptr[r], p1 = row_ptr[r + 1];
  const int hd = lane >> 4;
  const int ch = lane << 1;
  float acc0 = 0.f, acc1 = 0.f;

  int p = p0;
  for (; p + 8 <= p1; p += 8) {
    int cs[8];
    float ws[8];
    u32 hv[8];
#pragma unroll
    for (int i = 0; i < 8; ++i) cs[i] = col_csr[p + i];
#pragma unroll
    for (int i = 0; i < 8; ++i) ws[i] = b2f(an16[(size_t)(p + i) * 4 + hd]);
#pragma unroll
    for (int i = 0; i < 8; ++i) hv[i] = *(const u32*)&hb[(size_t)cs[i] * HC + ch];
#pragma unroll
    for (int i = 0; i < 8; ++i) {
      acc0 += ws[i] * b2f((u16)(hv[i] & 0xFFFFu));
      acc1 += ws[i] * b2f((u16)(hv[i] >> 16));
    }
  }
  for (; p < p1; ++p) {
    int c = col_csr[p];
    float w = b2f(an16[(size_t)p * 4 + hd]);
    u32 hv = *(const u32*)&hb[(size_t)c * HC + ch];
    acc0 += w * b2f((u16)(hv & 0xFFFFu));
    acc1 += w * b2f((u16)(hv >> 16));
  }
  acc0 += __shfl_xor(acc0, 16);
  acc0 += __shfl_xor(acc0, 32);
  acc1 += __shfl_xor(acc1, 16);
  acc1 += __shfl_xor(acc1, 32);
  if (lane < 16) {
    float2 o = make_float2(acc0 * 0.25f, acc1 * 0.25f);
    *(float2*)&out_mean[(size_t)r * 32 + (lane << 1)] = o;
  }
}

extern "C" void kernel_launch(void* const* d_in, const int* in_sizes, int n_in,
                              void* d_out, int out_size, void* d_ws, size_t ws_size,
                              hipStream_t stream) {
  const float* x = (const float*)d_in[0];
  const int* ei = (const int*)d_in[1];
  const float* W = (const float*)d_in[2];
  const float* attn = (const float*)d_in[3];
  const int* rowi = ei;
  const int* coli = ei + NEDGES;

  float* out_mean = (float*)d_out;
  float* alpha_out = (float*)d_out + (size_t)NNODES * 32;

  char* w = (char*)d_ws;
  u16* hb = (u16*)w;          w += (size_t)NNODES * HC * 2;       // 12.8 MB
  u16* an16 = (u16*)w;        w += (size_t)NEDGES * 4 * 2;        // 12.8 MB
  float* nrec = (float*)w;    w += (size_t)NNODES * NR * 4;       // 3.2 MB (64B/node)
  int* counts = (int*)w;      w += (size_t)NNODES * 4;
  int* bsum = (int*)w;        w += (size_t)256 * 4;
  int* boff = (int*)w;        w += (size_t)256 * 4;
  int* row_ptr = (int*)w;     w += (size_t)50016 * 4;
  u16* lslot = (u16*)w;       w += (size_t)NEDGES * 2;            // 3.2 MB
  u16* col_csr = (u16*)w;     w += (size_t)NEDGES * 2;            // 3.2 MB
  u32* chunk_hist = (u32*)w;  w += (size_t)NCHUNK * WORDS * 4;    // 12.8 MB
  u16* wt = (u16*)w;          w += (size_t)IN_CH * HC * 2;        // 64 KB

  k_wprep<<<(IN_CH * HC + 255) / 256, 256, 0, stream>>>(W, wt);
  k_chist<<<NCHUNK, 256, 0, stream>>>(rowi, chunk_hist, lslot);
  k_cscan<<<(WORDS + 63) / 64, 256, 0, stream>>>(chunk_hist, counts);
  k_scan1<<<NSB, 256, 0, stream>>>(counts, bsum);
  k_scan2<<<1, 256, 0, stream>>>(bsum, boff);
  k_scan3<<<NSB, 256, 0, stream>>>(counts, boff, row_ptr);
  k_gemscat<<<GEMM_BLOCKS + SCAT_BLOCKS, 256, 0, stream>>>(
      x, wt, attn, hb, nrec, rowi, coli, row_ptr, chunk_hist, lslot, col_csr);
  k_softmax<<<(NNODES + 3) / 4, 256, 0, stream>>>(col_csr, row_ptr, nrec, an16);
  k_alphaggr<<<AGGR_BLOCKS + ALPHA_BLOCKS, 256, 0, stream>>>(
      col_csr, row_ptr, an16, hb, out_mean, rowi, coli, nrec, alpha_out);
}

// Round 13
// 196.790 us; speedup vs baseline: 1.3803x; 1.0253x over previous
//
#include <hip/hip_runtime.h>

#define NNODES 50000
#define NEDGES 1600000
#define IN_CH 256
#define HEADS 4
#define OUT_CH 32
#define HC 128                       // HEADS*OUT_CH
#define NSB ((NNODES + 255) / 256)   // 196 scan3 blocks
#define NCHUNK 128
#define CE 12500                     // edges per chunk; 128*12500 == NEDGES
#define WORDS 25000                  // u32 words per chunk hist (2 u16 bins/word)
#define NSB2 ((WORDS + 63) / 64)     // 391 cscan blocks

#define GEMM_BLOCKS ((NNODES + 63) / 64)        // 782
#define SCAT_BLOCKS ((NEDGES + 1023) / 1024)    // 1563 (4 edges/thread)
#define AGGR_BLOCKS ((NNODES + 3) / 4)          // 12500
#define ALPHA_BLOCKS ((NEDGES + 255) / 256)     // 6250
#define WPREP_BLOCKS ((IN_CH * HC + 255) / 256) // 128

typedef unsigned int u32;
typedef unsigned short u16;
typedef short bf16x8 __attribute__((ext_vector_type(8)));   // 8 bf16 in 4 VGPRs
typedef u16 u16x8 __attribute__((ext_vector_type(8)));
typedef float f32x4 __attribute__((ext_vector_type(4)));

__device__ __forceinline__ float b2f(u16 s) { return __uint_as_float(((u32)s) << 16); }
__device__ __forceinline__ u16 f2b(float f) {
  u32 u = __float_as_uint(f);
  u32 r = (u + 0x7FFFu + ((u >> 16) & 1u)) >> 16;
  return (u16)r;
}
__device__ __forceinline__ float lrelu(float v) { return v >= 0.f ? v : 0.2f * v; }

// node record layout (16 floats = 64B): [0:4)=s_src, [4:8)=s_dst, [8:12)=mx, [12:16)=rden
#define NR 16

// ---- K1 (merged): blocks [0,NCHUNK) = chunked LDS histogram;
//      blocks [NCHUNK, +WPREP_BLOCKS) = W -> bf16 transpose-tile ----
__global__ __launch_bounds__(256) void k_whist(const int* __restrict__ rowi,
                                               u32* __restrict__ chunk_hist,
                                               u16* __restrict__ lslot,
                                               const float* __restrict__ W,
                                               u16* __restrict__ wt) {
  __shared__ u32 lh[WORDS];  // 100 KB
  const int tid = threadIdx.x;
  if (blockIdx.x >= NCHUNK) {
    // ---- wprep role ----
    int i = (blockIdx.x - NCHUNK) * 256 + tid;   // 0..32767
    if (i < IN_CH * HC) {
      int kk = i & 31;
      int n = (i >> 5) & 127;
      int kt = i >> 12;
      wt[i] = f2b(W[(size_t)(kt * 32 + kk) * HC + n]);
    }
    return;
  }
  // ---- chist role ----
  const int c = blockIdx.x;
  for (int i = tid; i < WORDS; i += 256) lh[i] = 0;
  __syncthreads();
  const int base = c * CE;
  for (int i = tid; i < CE; i += 256) {
    int e = base + i;
    int r = rowi[e];
    u32 sh = (u32)(r & 1) << 4;
    u32 old = atomicAdd(&lh[r >> 1], 1u << sh);
    lslot[e] = (u16)((old >> sh) & 0xFFFFu);
  }
  __syncthreads();
  u32* dst = chunk_hist + (size_t)c * WORDS;
  for (int i = tid; i < WORDS; i += 256) dst[i] = lh[i];
}

// ---- K2: in-place column scan of chunk_hist over chunks; per-row totals
//      + per-block (128-row) sums for the scan chain (scan1 folded in) ----
__global__ __launch_bounds__(256) void k_cscan(u32* __restrict__ chunk_hist,
                                               int* __restrict__ counts,
                                               int* __restrict__ bsum2) {
  __shared__ u32 tile[NCHUNK][64];  // 32 KB
  const int w0 = blockIdx.x * 64;
  const int tid = threadIdx.x;
  for (int i = tid; i < NCHUNK * 64; i += 256) {
    int c = i >> 6, wl = i & 63;
    int w = w0 + wl;
    tile[c][wl] = (w < WORDS) ? chunk_hist[(size_t)c * WORDS + w] : 0u;
  }
  __syncthreads();
  if (tid < 64) {
    u32 slo = 0, shi = 0;
    for (int c = 0; c < NCHUNK; ++c) {
      u32 v = tile[c][tid];
      tile[c][tid] = slo | (shi << 16);
      slo += v & 0xFFFFu;
      shi += v >> 16;
    }
    int w = w0 + tid;
    if (w < WORDS) {
      int r = w << 1;
      if (r < NNODES) counts[r] = (int)slo;
      if (r + 1 < NNODES) counts[r + 1] = (int)shi;
    }
    int tot = (int)(slo + shi);       // rows beyond NNODES contribute 0
#pragma unroll
    for (int m = 1; m < 64; m <<= 1) tot += __shfl_xor(tot, m);
    if (tid == 0) bsum2[blockIdx.x] = tot;
  }
  __syncthreads();
  for (int i = tid; i < NCHUNK * 64; i += 256) {
    int c = i >> 6, wl = i & 63;
    int w = w0 + wl;
    if (w < WORDS) chunk_hist[(size_t)c * WORDS + w] = tile[c][wl];
  }
}

// ---- K3: single-block exclusive scan of bsum2 (391 entries, 512 threads) ----
__global__ __launch_bounds__(512) void k_scan2(const int* __restrict__ bsum2,
                                               int* __restrict__ boff2) {
  __shared__ int s[512];
  int t = threadIdx.x;
  int v = (t < NSB2) ? bsum2[t] : 0;
  s[t] = v;
  __syncthreads();
  for (int off = 1; off < 512; off <<= 1) {
    int u = (t >= off) ? s[t - off] : 0;
    __syncthreads();
    s[t] += u;
    __syncthreads();
  }
  if (t < NSB2) boff2[t] = s[t] - v;  // exclusive
}

// ---- K4: per-256-row block scan of counts -> row_ptr (offset = boff2[2b]) ----
__global__ __launch_bounds__(256) void k_scan3(const int* __restrict__ counts,
                                               const int* __restrict__ boff2,
                                               int* __restrict__ row_ptr) {
  __shared__ int s[256];
  int t = threadIdx.x;
  int i = blockIdx.x * 256 + t;
  int v = (i < NNODES) ? counts[i] : 0;
  s[t] = v;
  __syncthreads();
  for (int off = 1; off < 256; off <<= 1) {
    int u = (t >= off) ? s[t - off] : 0;
    __syncthreads();
    s[t] += u;
    __syncthreads();
  }
  if (i < NNODES) row_ptr[i] = boff2[blockIdx.x << 1] + s[t] - v;
  if (i == 0) row_ptr[NNODES] = NEDGES;
}

// ---- K5 (merged): blocks [0,GEMM_BLOCKS) = MFMA gemm+scores;
//      blocks [GEMM_BLOCKS, +SCAT_BLOCKS) = CSR scatter (independent work) ----
__global__ __launch_bounds__(256) void k_gemscat(const float* __restrict__ x,
                                                 const u16* __restrict__ wt,
                                                 const float* __restrict__ attn,
                                                 u16* __restrict__ hb,
                                                 float* __restrict__ nrec,
                                                 const int* __restrict__ rowi,
                                                 const int* __restrict__ coli,
                                                 const int* __restrict__ row_ptr,
                                                 const u32* __restrict__ chunk_hist,
                                                 const u16* __restrict__ lslot,
                                                 u16* __restrict__ col_csr) {
  __shared__ union {
    struct {
      u16 xh[64 * 32];    // 4 KB, XOR-swizzled
      u16 xl[64 * 32];    // 4 KB
      u16 wh[128 * 32];   // 8 KB
    } st;
    float cbuf[64 * 132]; // 33.8 KB (row stride 132 f32)
  } L;
  __shared__ float sA[256];
  const int tid = threadIdx.x;

  if (blockIdx.x >= GEMM_BLOCKS) {
    // ---- scatter role: 4 edges per thread ----
    const int base = (blockIdx.x - GEMM_BLOCKS) * 1024 + tid;
#pragma unroll
    for (int k = 0; k < 4; ++k) {
      int e = base + k * 256;
      if (e < NEDGES) {
        int r = rowi[e];
        int c = e / CE;
        u32 word = chunk_hist[(size_t)c * WORDS + (r >> 1)];
        int off = (int)((word >> ((u32)(r & 1) << 4)) & 0xFFFFu);
        int pos = row_ptr[r] + off + (int)lslot[e];
        col_csr[pos] = (u16)coli[e];
      }
    }
    return;
  }

  // ---- gemm role ----
  const int wave = tid >> 6;
  const int lane = tid & 63;
  const int row0 = blockIdx.x * 64;
  sA[tid] = attn[tid];

  f32x4 acc[4][2] = {};
  const int frow = lane & 15;
  const int koff = (lane >> 4) << 4;

  const int sr = tid >> 2;
  const int skc = (tid & 3) << 3;
  const int sgrow = row0 + sr;
  const int sxb = (sr << 6) + (skc << 1);
  const int sxs = sxb ^ ((sr & 7) << 4);

  for (int kt = 0; kt < 8; ++kt) {
    {
      float4 v0 = make_float4(0.f, 0.f, 0.f, 0.f), v1 = v0;
      if (sgrow < NNODES) {
        const float* px = &x[(size_t)sgrow * IN_CH + kt * 32 + skc];
        v0 = *(const float4*)px;
        v1 = *(const float4*)(px + 4);
      }
      float vv[8] = {v0.x, v0.y, v0.z, v0.w, v1.x, v1.y, v1.z, v1.w};
      u16x8 hi, lo;
#pragma unroll
      for (int i = 0; i < 8; ++i) {
        u16 h = f2b(vv[i]);
        hi[i] = h;
        lo[i] = f2b(vv[i] - b2f(h));
      }
      *(u16x8*)((char*)L.st.xh + sxs) = hi;
      *(u16x8*)((char*)L.st.xl + sxs) = lo;
    }
#pragma unroll
    for (int li = 0; li < 2; ++li) {
      int i = tid + (li << 8);
      int col = i >> 2;
      int kb = (i & 3) << 4;
      u16x8 v = *(const u16x8*)((const char*)wt + (((size_t)(kt * 128 + col)) << 6) + kb);
      int sb = ((col << 6) + kb) ^ ((col & 7) << 4);
      *(u16x8*)((char*)L.st.wh + sb) = v;
    }
    __syncthreads();
    bf16x8 ah[4], al[4], bw[2];
#pragma unroll
    for (int mi = 0; mi < 4; ++mi) {
      int r = mi * 16 + frow;
      int sb = ((r << 6) + koff) ^ ((r & 7) << 4);
      ah[mi] = *(bf16x8*)((char*)L.st.xh + sb);
      al[mi] = *(bf16x8*)((char*)L.st.xl + sb);
    }
#pragma unroll
    for (int ni = 0; ni < 2; ++ni) {
      int c = (wave << 5) + ni * 16 + frow;
      int sb = ((c << 6) + koff) ^ ((c & 7) << 4);
      bw[ni] = *(bf16x8*)((char*)L.st.wh + sb);
    }
#pragma unroll
    for (int mi = 0; mi < 4; ++mi)
#pragma unroll
      for (int ni = 0; ni < 2; ++ni) {
        acc[mi][ni] = __builtin_amdgcn_mfma_f32_16x16x32_bf16(ah[mi], bw[ni], acc[mi][ni], 0, 0, 0);
        acc[mi][ni] = __builtin_amdgcn_mfma_f32_16x16x32_bf16(al[mi], bw[ni], acc[mi][ni], 0, 0, 0);
      }
    __syncthreads();
  }

#pragma unroll
  for (int mi = 0; mi < 4; ++mi)
#pragma unroll
    for (int ni = 0; ni < 2; ++ni) {
#pragma unroll
      for (int reg = 0; reg < 4; ++reg) {
        int row = mi * 16 + ((lane >> 4) << 2) + reg;
        int col = (wave << 5) + (ni << 4) + frow;
        L.cbuf[row * 132 + col] = acc[mi][ni][reg];
      }
    }
  __syncthreads();

  const int tc = tid & 31;
  const int tr = tid >> 5;
  const int head = tc >> 3;
  const int cb = (tc & 7) << 2;
  const float4 as4 = *(const float4*)&sA[head * 64 + cb];
  const float4 ad4 = *(const float4*)&sA[head * 64 + 32 + cb];
#pragma unroll
  for (int i = 0; i < 8; ++i) {
    int row = (tr << 3) + i;
    int grow = row0 + row;
    float4 v = *(const float4*)&L.cbuf[row * 132 + (tc << 2)];
    float ps = v.x * as4.x + v.y * as4.y + v.z * as4.z + v.w * as4.w;
    float pd = v.x * ad4.x + v.y * ad4.y + v.z * ad4.z + v.w * ad4.w;
    ps += __shfl_xor(ps, 1); ps += __shfl_xor(ps, 2); ps += __shfl_xor(ps, 4);
    pd += __shfl_xor(pd, 1); pd += __shfl_xor(pd, 2); pd += __shfl_xor(pd, 4);
    if (grow < NNODES) {
      u16 q[4] = {f2b(v.x), f2b(v.y), f2b(v.z), f2b(v.w)};
      *(ushort4*)&hb[(size_t)grow * HC + (tc << 2)] = *(ushort4*)q;
      if ((tc & 7) == 0) {
        nrec[(size_t)grow * NR + head] = ps;       // s_src
        nrec[(size_t)grow * NR + 4 + head] = pd;   // s_dst
      }
    }
  }
}

// ---- K6: per-row wave softmax: writes mx/rden into nrec + bf16 an in CSR order ----
__global__ __launch_bounds__(256) void k_softmax(const u16* __restrict__ col_csr,
                                                 const int* __restrict__ row_ptr,
                                                 float* __restrict__ nrec,
                                                 u16* __restrict__ an16) {
  const int wid = threadIdx.x >> 6;
  const int lane = threadIdx.x & 63;
  const int r = blockIdx.x * 4 + wid;
  if (r >= NNODES) return;
  const int p0 = row_ptr[r], p1 = row_ptr[r + 1];
  const int deg = p1 - p0;
  if (deg == 0) return;
  const float4 ss = *(const float4*)&nrec[(size_t)r * NR];
  const float NEG = -3.0e38f;

  if (deg <= 64) {
    float4 al = make_float4(NEG, NEG, NEG, NEG);
    if (lane < deg) {
      int c = col_csr[p0 + lane];
      float4 sd = *(const float4*)&nrec[(size_t)c * NR + 4];
      al.x = lrelu(ss.x + sd.x);
      al.y = lrelu(ss.y + sd.y);
      al.z = lrelu(ss.z + sd.z);
      al.w = lrelu(ss.w + sd.w);
    }
    float4 mx = al;
#pragma unroll
    for (int m = 1; m < 64; m <<= 1) {
      mx.x = fmaxf(mx.x, __shfl_xor(mx.x, m));
      mx.y = fmaxf(mx.y, __shfl_xor(mx.y, m));
      mx.z = fmaxf(mx.z, __shfl_xor(mx.z, m));
      mx.w = fmaxf(mx.w, __shfl_xor(mx.w, m));
    }
    float4 ex = make_float4(0.f, 0.f, 0.f, 0.f);
    if (lane < deg) {
      ex.x = __expf(al.x - mx.x);
      ex.y = __expf(al.y - mx.y);
      ex.z = __expf(al.z - mx.z);
      ex.w = __expf(al.w - mx.w);
    }
    float4 sm = ex;
#pragma unroll
    for (int m = 1; m < 64; m <<= 1) {
      sm.x += __shfl_xor(sm.x, m);
      sm.y += __shfl_xor(sm.y, m);
      sm.z += __shfl_xor(sm.z, m);
      sm.w += __shfl_xor(sm.w, m);
    }
    float4 rd = make_float4(1.f / sm.x, 1.f / sm.y, 1.f / sm.z, 1.f / sm.w);
    if (lane == 0) {
      *(float4*)&nrec[(size_t)r * NR + 8] = mx;
      *(float4*)&nrec[(size_t)r * NR + 12] = rd;
    }
    if (lane < deg) {
      u16 q[4] = {f2b(ex.x * rd.x), f2b(ex.y * rd.y), f2b(ex.z * rd.z), f2b(ex.w * rd.w)};
      *(ushort4*)&an16[(size_t)(p0 + lane) * 4] = *(ushort4*)q;
    }
  } else {
    float4 mx = make_float4(NEG, NEG, NEG, NEG);
    for (int p = p0 + lane; p < p1; p += 64) {
      int c = col_csr[p];
      float4 sd = *(const float4*)&nrec[(size_t)c * NR + 4];
      mx.x = fmaxf(mx.x, lrelu(ss.x + sd.x));
      mx.y = fmaxf(mx.y, lrelu(ss.y + sd.y));
      mx.z = fmaxf(mx.z, lrelu(ss.z + sd.z));
      mx.w = fmaxf(mx.w, lrelu(ss.w + sd.w));
    }
#pragma unroll
    for (int m = 1; m < 64; m <<= 1) {
      mx.x = fmaxf(mx.x, __shfl_xor(mx.x, m));
      mx.y = fmaxf(mx.y, __shfl_xor(mx.y, m));
      mx.z = fmaxf(mx.z, __shfl_xor(mx.z, m));
      mx.w = fmaxf(mx.w, __shfl_xor(mx.w, m));
    }
    float4 sm = make_float4(0.f, 0.f, 0.f, 0.f);
    for (int p = p0 + lane; p < p1; p += 64) {
      int c = col_csr[p];
      float4 sd = *(const float4*)&nrec[(size_t)c * NR + 4];
      sm.x += __expf(lrelu(ss.x + sd.x) - mx.x);
      sm.y += __expf(lrelu(ss.y + sd.y) - mx.y);
      sm.z += __expf(lrelu(ss.z + sd.z) - mx.z);
      sm.w += __expf(lrelu(ss.w + sd.w) - mx.w);
    }
#pragma unroll
    for (int m = 1; m < 64; m <<= 1) {
      sm.x += __shfl_xor(sm.x, m);
      sm.y += __shfl_xor(sm.y, m);
      sm.z += __shfl_xor(sm.z, m);
      sm.w += __shfl_xor(sm.w, m);
    }
    float4 rd = make_float4(1.f / sm.x, 1.f / sm.y, 1.f / sm.z, 1.f / sm.w);
    if (lane == 0) {
      *(float4*)&nrec[(size_t)r * NR + 8] = mx;
      *(float4*)&nrec[(size_t)r * NR + 12] = rd;
    }
    for (int p = p0 + lane; p < p1; p += 64) {
      int c = col_csr[p];
      float4 sd = *(const float4*)&nrec[(size_t)c * NR + 4];
      float4 ex;
      ex.x = __expf(lrelu(ss.x + sd.x) - mx.x) * rd.x;
      ex.y = __expf(lrelu(ss.y + sd.y) - mx.y) * rd.y;
      ex.z = __expf(lrelu(ss.z + sd.z) - mx.z) * rd.z;
      ex.w = __expf(lrelu(ss.w + sd.w) - mx.w) * rd.w;
      u16 q[4] = {f2b(ex.x), f2b(ex.y), f2b(ex.z), f2b(ex.w)};
      *(ushort4*)&an16[(size_t)p * 4] = *(ushort4*)q;
    }
  }
}

// ---- K7 (merged): blocks [0,AGGR_BLOCKS) = aggregation (long pole);
//      blocks [AGGR_BLOCKS, +ALPHA_BLOCKS) = alpha_norm edge-order write ----
__global__ __launch_bounds__(256) void k_alphaggr(const u16* __restrict__ col_csr,
                                                  const int* __restrict__ row_ptr,
                                                  const u16* __restrict__ an16,
                                                  const u16* __restrict__ hb,
                                                  float* __restrict__ out_mean,
                                                  const int* __restrict__ rowi,
                                                  const int* __restrict__ coli,
                                                  const float* __restrict__ nrec,
                                                  float* __restrict__ alpha_out) {
  if (blockIdx.x >= AGGR_BLOCKS) {
    // ---- alphaf role ----
    int e = (blockIdx.x - AGGR_BLOCKS) * 256 + threadIdx.x;
    if (e >= NEDGES) return;
    int r = rowi[e], c = coli[e];
    const float* nr = &nrec[(size_t)r * NR];
    float4 ss = *(const float4*)(nr);
    float4 m4 = *(const float4*)(nr + 8);
    float4 rd = *(const float4*)(nr + 12);
    float4 sd = *(const float4*)&nrec[(size_t)c * NR + 4];
    float4 an;
    an.x = __expf(lrelu(ss.x + sd.x) - m4.x) * rd.x;
    an.y = __expf(lrelu(ss.y + sd.y) - m4.y) * rd.y;
    an.z = __expf(lrelu(ss.z + sd.z) - m4.z) * rd.z;
    an.w = __expf(lrelu(ss.w + sd.w) - m4.w) * rd.w;
    *(float4*)&alpha_out[(size_t)e * 4] = an;
    return;
  }
  // ---- aggr role ----
  const int wid = threadIdx.x >> 6;
  const int lane = threadIdx.x & 63;
  const int r = blockIdx.x * 4 + wid;
  if (r >= NNODES) return;
  const int p0 = row_ptr[r], p1 = row_ptr[r + 1];
  const int hd = lane >> 4;
  const int ch = lane << 1;
  float acc0 = 0.f, acc1 = 0.f;

  int p = p0;
  for (; p + 8 <= p1; p += 8) {
    int cs[8];
    float ws[8];
    u32 hv[8];
#pragma unroll
    for (int i = 0; i < 8; ++i) cs[i] = col_csr[p + i];
#pragma unroll
    for (int i = 0; i < 8; ++i) ws[i] = b2f(an16[(size_t)(p + i) * 4 + hd]);
#pragma unroll
    for (int i = 0; i < 8; ++i) hv[i] = *(const u32*)&hb[(size_t)cs[i] * HC + ch];
#pragma unroll
    for (int i = 0; i < 8; ++i) {
      acc0 += ws[i] * b2f((u16)(hv[i] & 0xFFFFu));
      acc1 += ws[i] * b2f((u16)(hv[i] >> 16));
    }
  }
  for (; p < p1; ++p) {
    int c = col_csr[p];
    float w = b2f(an16[(size_t)p * 4 + hd]);
    u32 hv = *(const u32*)&hb[(size_t)c * HC + ch];
    acc0 += w * b2f((u16)(hv & 0xFFFFu));
    acc1 += w * b2f((u16)(hv >> 16));
  }
  acc0 += __shfl_xor(acc0, 16);
  acc0 += __shfl_xor(acc0, 32);
  acc1 += __shfl_xor(acc1, 16);
  acc1 += __shfl_xor(acc1, 32);
  if (lane < 16) {
    float2 o = make_float2(acc0 * 0.25f, acc1 * 0.25f);
    *(float2*)&out_mean[(size_t)r * 32 + (lane << 1)] = o;
  }
}

extern "C" void kernel_launch(void* const* d_in, const int* in_sizes, int n_in,
                              void* d_out, int out_size, void* d_ws, size_t ws_size,
                              hipStream_t stream) {
  const float* x = (const float*)d_in[0];
  const int* ei = (const int*)d_in[1];
  const float* W = (const float*)d_in[2];
  const float* attn = (const float*)d_in[3];
  const int* rowi = ei;
  const int* coli = ei + NEDGES;

  float* out_mean = (float*)d_out;
  float* alpha_out = (float*)d_out + (size_t)NNODES * 32;

  char* w = (char*)d_ws;
  u16* hb = (u16*)w;          w += (size_t)NNODES * HC * 2;       // 12.8 MB
  u16* an16 = (u16*)w;        w += (size_t)NEDGES * 4 * 2;        // 12.8 MB
  float* nrec = (float*)w;    w += (size_t)NNODES * NR * 4;       // 3.2 MB (64B/node)
  int* counts = (int*)w;      w += (size_t)NNODES * 4;
  int* bsum2 = (int*)w;       w += (size_t)512 * 4;
  int* boff2 = (int*)w;       w += (size_t)512 * 4;
  int* row_ptr = (int*)w;     w += (size_t)50016 * 4;
  u16* lslot = (u16*)w;       w += (size_t)NEDGES * 2;            // 3.2 MB
  u16* col_csr = (u16*)w;     w += (size_t)NEDGES * 2;            // 3.2 MB
  u32* chunk_hist = (u32*)w;  w += (size_t)NCHUNK * WORDS * 4;    // 12.8 MB
  u16* wt = (u16*)w;          w += (size_t)IN_CH * HC * 2;        // 64 KB

  k_whist<<<NCHUNK + WPREP_BLOCKS, 256, 0, stream>>>(rowi, chunk_hist, lslot, W, wt);
  k_cscan<<<NSB2, 256, 0, stream>>>(chunk_hist, counts, bsum2);
  k_scan2<<<1, 512, 0, stream>>>(bsum2, boff2);
  k_scan3<<<NSB, 256, 0, stream>>>(counts, boff2, row_ptr);
  k_gemscat<<<GEMM_BLOCKS + SCAT_BLOCKS, 256, 0, stream>>>(
      x, wt, attn, hb, nrec, rowi, coli, row_ptr, chunk_hist, lslot, col_csr);
  k_softmax<<<(NNODES + 3) / 4, 256, 0, stream>>>(col_csr, row_ptr, nrec, an16);
  k_alphaggr<<<AGGR_BLOCKS + ALPHA_BLOCKS, 256, 0, stream>>>(
      col_csr, row_ptr, an16, hb, out_mean, rowi, coli, nrec, alpha_out);
}